// Round 7
// baseline (218.849 us; speedup 1.0000x reference)
//
#include <hip/hip_runtime.h>
#include <hip/hip_bf16.h>
#include <stdint.h>

#define DIMK 256
#define DIMV 384
#define NSEQ 1024
#define NHEAD 6
#define IDXCAP 256

typedef __attribute__((ext_vector_type(8))) short short8;
typedef __attribute__((ext_vector_type(4))) float floatx4;

__device__ __forceinline__ unsigned short f2b(float f){
  unsigned int x = __float_as_uint(f);
  return (unsigned short)((x + 0x7fffu + ((x >> 16) & 1u)) >> 16);
}
__device__ __forceinline__ unsigned int pack2(float a, float b){
  return (unsigned int)f2b(a) | ((unsigned int)f2b(b) << 16);
}
__device__ __forceinline__ float blo(unsigned int u){ return __uint_as_float(u << 16); }
__device__ __forceinline__ float bhi(unsigned int u){ return __uint_as_float(u & 0xffff0000u); }

// transpose + convert: W [256][384] f32 -> Wt [384][256] bf16 (both weights)
__global__ void conv_w_kernel(const float* __restrict__ WQ, const float* __restrict__ WK,
                              unsigned short* __restrict__ wqt, unsigned short* __restrict__ wkt){
  int i = blockIdx.x * 256 + threadIdx.x;
  const float* W; unsigned short* O; int idx;
  if (i < 98304){ W = WQ; O = wqt; idx = i; }
  else          { W = WK; O = wkt; idx = i - 98304; }
  int n = idx >> 8;
  int k = idx & 255;
  O[idx] = f2b(W[(size_t)k * 384 + n]);
}

// A-row ballot compaction: one wave per row -> u16 idx list (cap 256) + count.
__global__ __launch_bounds__(256) void compact_kernel(const float* __restrict__ A,
    unsigned short* __restrict__ idxb, int* __restrict__ Mb){
  int r = blockIdx.x * 4 + (threadIdx.x >> 6);
  int lane = threadIdx.x & 63;
  const float4* arow = (const float4*)(A + (size_t)r * NSEQ);
  float4 av[4];
  #pragma unroll
  for (int c = 0; c < 4; ++c) av[c] = arow[c * 64 + lane];
  unsigned long long lmask = (1ull << lane) - 1ull;
  unsigned short* row = idxb + (size_t)r * IDXCAP;
  int base = 0;
  #pragma unroll
  for (int c = 0; c < 4; ++c){
    #pragma unroll
    for (int e = 0; e < 4; ++e){
      float a = (e==0)?av[c].x:(e==1)?av[c].y:(e==2)?av[c].z:av[c].w;
      bool on = a > 0.5f;
      unsigned long long m = __ballot(on);
      int pos = base + __popcll(m & lmask);
      if (on && pos < IDXCAP) row[pos] = (unsigned short)((c * 64 + lane) * 4 + e);
      base += __popcll(m);
    }
  }
  for (int j = base + lane; j < 128; j += 64) row[j] = 0;   // fast path reads [0,128)
  if (lane == 0) Mb[r] = base;
}

// Merged projections.  z=0: q = Q@WQ+bQ -> f32 ROW-MAJOR [row][384]
//                      z=1: k = V@WK+bK -> bf16 HEAD-MAJOR [(b*6+h)*1024+n][64]
__global__ __launch_bounds__(256) void proj2_kernel(
    const float* __restrict__ Q, const float* __restrict__ V,
    const unsigned short* __restrict__ wqt, const unsigned short* __restrict__ wkt,
    const float* __restrict__ bQ, const float* __restrict__ bK,
    float* __restrict__ qout, unsigned short* __restrict__ kout)
{
  __shared__ uint4 lA[512];
  __shared__ uint4 lB[864];
  int which = blockIdx.z;
  const float* X = which ? V : Q;
  const unsigned short* Wt = which ? wkt : wqt;
  const float* bias = which ? bK : bQ;

  int t = threadIdx.x;
  int lane = t & 63, wave = t >> 6;
  int wm = wave >> 1, wn = wave & 1;
  int rb = blockIdx.x * 64;
  int nb = blockIdx.y * 96;
  floatx4 acc[2][3];
  #pragma unroll
  for (int mi = 0; mi < 2; ++mi)
    #pragma unroll
    for (int ni = 0; ni < 3; ++ni) acc[mi][ni] = (floatx4){0.f, 0.f, 0.f, 0.f};

  for (int it = 0; it < 4; ++it){
    int k0 = it * 64;
    #pragma unroll
    for (int i = 0; i < 2; ++i){
      int c = t + i * 256;
      int kc = c >> 6, row = c & 63;
      const float* src = X + (size_t)(rb + row) * DIMK + k0 + kc * 8;
      float4 f0 = *(const float4*)src;
      float4 f1 = *(const float4*)(src + 4);
      uint4 w;
      w.x = pack2(f0.x, f0.y); w.y = pack2(f0.z, f0.w);
      w.z = pack2(f1.x, f1.y); w.w = pack2(f1.z, f1.w);
      lA[c] = w;
    }
    #pragma unroll
    for (int i = 0; i < 3; ++i){
      int c = t + i * 256;
      int n = c >> 3, kc = c & 7;
      uint4 v = *(const uint4*)(Wt + (size_t)(nb + n) * DIMK + k0 + kc * 8);
      lB[n * 9 + kc] = v;
    }
    __syncthreads();
    #pragma unroll
    for (int kk = 0; kk < 2; ++kk){
      int kc  = kk * 4 + (lane >> 4);
      int r16 = lane & 15;
      short8 af[2], bf[3];
      #pragma unroll
      for (int mi = 0; mi < 2; ++mi)
        af[mi] = *(const short8*)&lA[kc * 64 + wm * 32 + mi * 16 + r16];
      #pragma unroll
      for (int ni = 0; ni < 3; ++ni)
        bf[ni] = *(const short8*)&lB[(wn * 48 + ni * 16 + r16) * 9 + kc];
      #pragma unroll
      for (int mi = 0; mi < 2; ++mi)
        #pragma unroll
        for (int ni = 0; ni < 3; ++ni)
          acc[mi][ni] = __builtin_amdgcn_mfma_f32_16x16x32_bf16(af[mi], bf[ni], acc[mi][ni], 0, 0, 0);
    }
    __syncthreads();
  }
  int r16 = lane & 15, rq = lane >> 4;
  #pragma unroll
  for (int ni = 0; ni < 3; ++ni){
    int col = nb + wn * 48 + ni * 16 + r16;
    float bv = bias[col];
    int h = col >> 6, d = col & 63;
    #pragma unroll
    for (int mi = 0; mi < 2; ++mi){
      #pragma unroll
      for (int q = 0; q < 4; ++q){
        int row = rb + wm * 32 + mi * 16 + rq * 4 + q;
        float v = acc[mi][ni][q] + bv;
        if (which){
          int bb = row >> 10, n = row & 1023;
          size_t dst = ((size_t)(bb * NHEAD + h) * NSEQ + n) * 64 + d;
          kout[dst] = f2b(v);
        } else {
          qout[(size_t)row * DIMV + col] = v;
        }
      }
    }
  }
}

// 64-dim dot: k row bf16 (128B), q row f32 in LDS (uniform-address broadcast)
__device__ __forceinline__ float dotqk(const unsigned short* __restrict__ krow,
                                       const float* __restrict__ qrow){
  const uint4* kp = (const uint4*)krow;
  float z = 0.f;
  #pragma unroll
  for (int c = 0; c < 8; ++c){
    uint4 k = kp[c];
    const float4* qp = (const float4*)(qrow + c * 8);
    float4 qa = qp[0], qb = qp[1];
    z += blo(k.x)*qa.x + bhi(k.x)*qa.y + blo(k.y)*qa.z + bhi(k.y)*qa.w
       + blo(k.z)*qb.x + bhi(k.z)*qb.y + blo(k.w)*qb.z + bhi(k.w)*qb.w;
  }
  return z;
}

__device__ __forceinline__ void red2(float& s, float& n){
  #pragma unroll
  for (int o = 1; o < 64; o <<= 1){ s += __shfl_xor(s, o); n += __shfl_xor(n, o); }
}
__device__ __forceinline__ void red6(float* s){
  #pragma unroll
  for (int o = 1; o < 64; o <<= 1){
    #pragma unroll
    for (int h = 0; h < 6; ++h) s[h] += __shfl_xor(s[h], o);
  }
}

// ONE WAVE per row, ALL 6 HEADS: idx/M/q loaded once per row, 6 independent
// dot+Michelot chains per lane, ballot-based support counts, LDS-staged
// per-head output (one reused 4 KB row), nontemporal streaming stores.
__global__ __launch_bounds__(64) void attn_kernel(const float* __restrict__ qb,
    const unsigned short* __restrict__ kb2, const unsigned short* __restrict__ idxb,
    const int* __restrict__ Mb, float* __restrict__ out)
{
  __shared__ float obuf[NSEQ];
  __shared__ float qsh[DIMV];

  int bid = blockIdx.x;
  int x = bid & 7;            // batch == XCD
  int n = bid >> 3;           // row within batch
  int r = (x << 10) + n;
  int lane = threadIdx.x;

  const float scale = 0.05103103630798288f;    // 1/sqrt(384)
  const float* qrow = qb + (size_t)r * DIMV;
  #pragma unroll
  for (int i = 0; i < 6; ++i) qsh[i * 64 + lane] = qrow[i * 64 + lane] * scale;

  int M = Mb[r];
  const unsigned short* ip = idxb + (size_t)r * IDXCAP;
  const unsigned short* kbase = kb2 + (size_t)x * NHEAD * NSEQ * 64;
  float* orow = out + (size_t)r * (NHEAD * NSEQ);
  float4 zf = make_float4(0.f, 0.f, 0.f, 0.f);

  if (M <= 128){
    bool haveC2 = M > 64;
    bool a0 = lane < M;
    bool a1 = haveC2 && (64 + lane) < M;
    int id0 = ip[lane];
    int id1 = haveC2 ? ip[64 + lane] : 0;

    float z0[6], z1[6];
    #pragma unroll
    for (int h = 0; h < 6; ++h)
      z0[h] = dotqk(kbase + ((size_t)h * NSEQ + id0) * 64, qsh + h * 64);
    if (haveC2){
      #pragma unroll
      for (int h = 0; h < 6; ++h)
        z1[h] = dotqk(kbase + ((size_t)h * NSEQ + id1) * 64, qsh + h * 64);
    } else {
      #pragma unroll
      for (int h = 0; h < 6; ++h) z1[h] = 0.f;
    }

    // Michelot fixed point per head: tau=(sum_{z>tau} z - 1)/|{z>tau}|,
    // support initialized to all M entries, shrinks monotonically.
    float s[6], tau[6];
    int cnt[6], pcnt[6];
    #pragma unroll
    for (int h = 0; h < 6; ++h)
      s[h] = (a0 ? z0[h] : 0.f) + (a1 ? z1[h] : 0.f);
    red6(s);
    float invM = 1.f / (float)M;
    #pragma unroll
    for (int h = 0; h < 6; ++h){ tau[h] = (s[h] - 1.f) * invM; pcnt[h] = M; }
    #pragma unroll 1
    for (int it = 0; it < 64; ++it){
      #pragma unroll
      for (int h = 0; h < 6; ++h){
        bool m0 = a0 && z0[h] > tau[h];
        bool m1 = a1 && z1[h] > tau[h];
        cnt[h] = __popcll(__ballot(m0)) + __popcll(__ballot(m1));
        s[h] = (m0 ? z0[h] : 0.f) + (m1 ? z1[h] : 0.f);
      }
      red6(s);
      bool any = false;
      #pragma unroll
      for (int h = 0; h < 6; ++h){
        if (cnt[h] != pcnt[h]){
          any = true;
          tau[h] = (s[h] - 1.f) / (float)cnt[h];
          pcnt[h] = cnt[h];
        }
      }
      if (!any) break;
    }

    // per-head: zero LDS row, scatter nonzeros, stream out (same-wave DS
    // ordering makes the zero->scatter->read sequence safe, no barriers)
    #pragma unroll 1
    for (int h = 0; h < 6; ++h){
      #pragma unroll
      for (int v = 0; v < 4; ++v) ((float4*)obuf)[v * 64 + lane] = zf;
      if (a0){ float p = z0[h] - tau[h]; if (p > 0.f) obuf[id0] = p; }
      if (a1){ float p = z1[h] - tau[h]; if (p > 0.f) obuf[id1] = p; }
      float* od = orow + h * NSEQ;
      #pragma unroll
      for (int v = 0; v < 4; ++v){
        floatx4 w = ((const floatx4*)obuf)[v * 64 + lane];
        __builtin_nontemporal_store(w, &((floatx4*)od)[v * 64 + lane]);
      }
    }
  } else {
    // ---- generic fallback (M>128, ~never) ----
    if (M > IDXCAP) M = IDXCAP;
    #pragma unroll 1
    for (int h = 0; h < 6; ++h){
      const float* qr = qsh + h * 64;
      #pragma unroll 1
      for (int j0 = 0; j0 < M; j0 += 64){
        int jj = j0 + lane;
        if (jj < M){
          int idx = ip[jj];
          obuf[jj] = dotqk(kbase + ((size_t)h * NSEQ + idx) * 64, qr);
        }
      }
      float s = 0.f, c = 0.f;
      for (int jj = lane; jj < M; jj += 64){ s += obuf[jj]; c += 1.f; }
      red2(s, c);
      float tau = (s - 1.f) / c, pn = c;
      #pragma unroll 1
      for (int it = 0; it < 64; ++it){
        s = 0.f; c = 0.f;
        for (int jj = lane; jj < M; jj += 64){
          float z = obuf[jj];
          if (z > tau){ s += z; c += 1.f; }
        }
        red2(s, c);
        if (c == pn) break;
        tau = (s - 1.f) / c; pn = c;
      }
      float* od = orow + h * NSEQ;
      #pragma unroll
      for (int v = 0; v < 4; ++v) ((float4*)od)[v * 64 + lane] = zf;
      asm volatile("s_waitcnt vmcnt(0)" ::: "memory");
      for (int jj = lane; jj < M; jj += 64){
        float q = obuf[jj] - tau;
        int idx = ip[jj];
        if (q > 0.f) od[idx] = q;
      }
    }
  }
}

extern "C" void kernel_launch(void* const* d_in, const int* in_sizes, int n_in,
                              void* d_out, int out_size, void* d_ws, size_t ws_size,
                              hipStream_t stream) {
  const float* Q  = (const float*)d_in[0];
  const float* V  = (const float*)d_in[1];
  const float* A  = (const float*)d_in[2];
  const float* WQ = (const float*)d_in[3];
  const float* bQ = (const float*)d_in[4];
  const float* WK = (const float*)d_in[5];
  const float* bK = (const float*)d_in[6];
  float* out = (float*)d_out;

  char* ws = (char*)d_ws;
  float*          qb   = (float*)ws;                                   // 12.58 MB f32 row-major, scaled in attn
  unsigned short* kb2  = (unsigned short*)(ws + (size_t)12582912);     //  6.29 MB bf16 head-major
  unsigned short* wqt  = (unsigned short*)(ws + (size_t)18874368);
  unsigned short* wkt  = wqt + 98304;
  unsigned short* idxb = (unsigned short*)(ws + (size_t)19267584);     //  4.19 MB
  int*            Mb   = (int*)(ws + (size_t)23461888);                //  32 KB
  (void)in_sizes; (void)n_in; (void)out_size; (void)ws_size;

  conv_w_kernel<<<768, 256, 0, stream>>>(WQ, WK, wqt, wkt);
  compact_kernel<<<2048, 256, 0, stream>>>(A, idxb, Mb);
  proj2_kernel<<<dim3(128, 4, 2), 256, 0, stream>>>(Q, V, wqt, wkt, bQ, bK, qb, kb2);
  attn_kernel<<<8192, 64, 0, stream>>>(qb, kb2, idxb, Mb, out);
}

// Round 8
// 143.966 us; speedup vs baseline: 1.5201x; 1.5201x over previous
//
#include <hip/hip_runtime.h>
#include <hip/hip_bf16.h>
#include <stdint.h>

#define DIMK 256
#define DIMV 384
#define NSEQ 1024
#define NHEAD 6
#define IDXCAP 256

typedef __attribute__((ext_vector_type(8))) short short8;
typedef __attribute__((ext_vector_type(4))) float floatx4;

__device__ __forceinline__ unsigned short f2b(float f){
  unsigned int x = __float_as_uint(f);
  return (unsigned short)((x + 0x7fffu + ((x >> 16) & 1u)) >> 16);
}
__device__ __forceinline__ unsigned int pack2(float a, float b){
  return (unsigned int)f2b(a) | ((unsigned int)f2b(b) << 16);
}
__device__ __forceinline__ float blo(unsigned int u){ return __uint_as_float(u << 16); }
__device__ __forceinline__ float bhi(unsigned int u){ return __uint_as_float(u & 0xffff0000u); }

// transpose + convert: W [256][384] f32 -> Wt [384][256] bf16 (both weights)
__global__ void conv_w_kernel(const float* __restrict__ WQ, const float* __restrict__ WK,
                              unsigned short* __restrict__ wqt, unsigned short* __restrict__ wkt){
  int i = blockIdx.x * 256 + threadIdx.x;
  const float* W; unsigned short* O; int idx;
  if (i < 98304){ W = WQ; O = wqt; idx = i; }
  else          { W = WK; O = wkt; idx = i - 98304; }
  int n = idx >> 8;
  int k = idx & 255;
  O[idx] = f2b(W[(size_t)k * 384 + n]);
}

// A-row ballot compaction: one wave per row -> u16 idx list (cap 256) + count.
__global__ __launch_bounds__(256) void compact_kernel(const float* __restrict__ A,
    unsigned short* __restrict__ idxb, int* __restrict__ Mb){
  int r = blockIdx.x * 4 + (threadIdx.x >> 6);
  int lane = threadIdx.x & 63;
  const float4* arow = (const float4*)(A + (size_t)r * NSEQ);
  float4 av[4];
  #pragma unroll
  for (int c = 0; c < 4; ++c) av[c] = arow[c * 64 + lane];
  unsigned long long lmask = (1ull << lane) - 1ull;
  unsigned short* row = idxb + (size_t)r * IDXCAP;
  int base = 0;
  #pragma unroll
  for (int c = 0; c < 4; ++c){
    #pragma unroll
    for (int e = 0; e < 4; ++e){
      float a = (e==0)?av[c].x:(e==1)?av[c].y:(e==2)?av[c].z:av[c].w;
      bool on = a > 0.5f;
      unsigned long long m = __ballot(on);
      int pos = base + __popcll(m & lmask);
      if (on && pos < IDXCAP) row[pos] = (unsigned short)((c * 64 + lane) * 4 + e);
      base += __popcll(m);
    }
  }
  for (int j = base + lane; j < 128; j += 64) row[j] = 0;   // fast path reads [0,128)
  if (lane == 0) Mb[r] = base;
}

// Merged projections, both HEAD-MAJOR [(b*6+h)*1024+n][64]:
//   z=0: q = Q@WQ+bQ -> f32    z=1: k = V@WK+bK -> bf16
__global__ __launch_bounds__(256) void proj2_kernel(
    const float* __restrict__ Q, const float* __restrict__ V,
    const unsigned short* __restrict__ wqt, const unsigned short* __restrict__ wkt,
    const float* __restrict__ bQ, const float* __restrict__ bK,
    float* __restrict__ qout, unsigned short* __restrict__ kout)
{
  __shared__ uint4 lA[512];
  __shared__ uint4 lB[864];
  int which = blockIdx.z;
  const float* X = which ? V : Q;
  const unsigned short* Wt = which ? wkt : wqt;
  const float* bias = which ? bK : bQ;

  int t = threadIdx.x;
  int lane = t & 63, wave = t >> 6;
  int wm = wave >> 1, wn = wave & 1;
  int rb = blockIdx.x * 64;
  int nb = blockIdx.y * 96;
  floatx4 acc[2][3];
  #pragma unroll
  for (int mi = 0; mi < 2; ++mi)
    #pragma unroll
    for (int ni = 0; ni < 3; ++ni) acc[mi][ni] = (floatx4){0.f, 0.f, 0.f, 0.f};

  for (int it = 0; it < 4; ++it){
    int k0 = it * 64;
    #pragma unroll
    for (int i = 0; i < 2; ++i){
      int c = t + i * 256;
      int kc = c >> 6, row = c & 63;
      const float* src = X + (size_t)(rb + row) * DIMK + k0 + kc * 8;
      float4 f0 = *(const float4*)src;
      float4 f1 = *(const float4*)(src + 4);
      uint4 w;
      w.x = pack2(f0.x, f0.y); w.y = pack2(f0.z, f0.w);
      w.z = pack2(f1.x, f1.y); w.w = pack2(f1.z, f1.w);
      lA[c] = w;
    }
    #pragma unroll
    for (int i = 0; i < 3; ++i){
      int c = t + i * 256;
      int n = c >> 3, kc = c & 7;
      uint4 v = *(const uint4*)(Wt + (size_t)(nb + n) * DIMK + k0 + kc * 8);
      lB[n * 9 + kc] = v;
    }
    __syncthreads();
    #pragma unroll
    for (int kk = 0; kk < 2; ++kk){
      int kc  = kk * 4 + (lane >> 4);
      int r16 = lane & 15;
      short8 af[2], bf[3];
      #pragma unroll
      for (int mi = 0; mi < 2; ++mi)
        af[mi] = *(const short8*)&lA[kc * 64 + wm * 32 + mi * 16 + r16];
      #pragma unroll
      for (int ni = 0; ni < 3; ++ni)
        bf[ni] = *(const short8*)&lB[(wn * 48 + ni * 16 + r16) * 9 + kc];
      #pragma unroll
      for (int mi = 0; mi < 2; ++mi)
        #pragma unroll
        for (int ni = 0; ni < 3; ++ni)
          acc[mi][ni] = __builtin_amdgcn_mfma_f32_16x16x32_bf16(af[mi], bf[ni], acc[mi][ni], 0, 0, 0);
    }
    __syncthreads();
  }
  int r16 = lane & 15, rq = lane >> 4;
  #pragma unroll
  for (int ni = 0; ni < 3; ++ni){
    int col = nb + wn * 48 + ni * 16 + r16;
    float bv = bias[col];
    int h = col >> 6, d = col & 63;
    #pragma unroll
    for (int mi = 0; mi < 2; ++mi){
      #pragma unroll
      for (int q = 0; q < 4; ++q){
        int row = rb + wm * 32 + mi * 16 + rq * 4 + q;
        int bb = row >> 10, n = row & 1023;
        size_t dst = ((size_t)(bb * NHEAD + h) * NSEQ + n) * 64 + d;
        float v = acc[mi][ni][q] + bv;
        if (which) kout[dst] = f2b(v);
        else       qout[dst] = v;
      }
    }
  }
}

// 64-dim dot: k row bf16 (128B), q row f32 in LDS (uniform-address broadcast)
__device__ __forceinline__ float dotqk(const unsigned short* __restrict__ krow,
                                       const float* __restrict__ qrow){
  const uint4* kp = (const uint4*)krow;
  float z = 0.f;
  #pragma unroll
  for (int c = 0; c < 8; ++c){
    uint4 k = kp[c];
    const float4* qp = (const float4*)(qrow + c * 8);
    float4 qa = qp[0], qb = qp[1];
    z += blo(k.x)*qa.x + bhi(k.x)*qa.y + blo(k.y)*qa.z + bhi(k.y)*qa.w
       + blo(k.z)*qb.x + bhi(k.z)*qb.y + blo(k.w)*qb.z + bhi(k.w)*qb.w;
  }
  return z;
}

__device__ __forceinline__ void red2(float& s, float& n){
  #pragma unroll
  for (int o = 1; o < 64; o <<= 1){ s += __shfl_xor(s, o); n += __shfl_xor(n, o); }
}
__device__ __forceinline__ void red4(float& a, float& b, float& c, float& d){
  #pragma unroll
  for (int o = 1; o < 64; o <<= 1){
    a += __shfl_xor(a, o); b += __shfl_xor(b, o);
    c += __shfl_xor(c, o); d += __shfl_xor(d, o);
  }
}

// ONE WAVE per workgroup, one (row-pair, head) each: wave-granular scheduling.
// Plain (L2 write-combined) stores — nt stores caused 2.3x HBM write
// amplification (r7: WRITE 448 MB vs 226 MB).
__global__ __launch_bounds__(64) void attn_kernel(const float* __restrict__ qb2,
    const unsigned short* __restrict__ kb2, const unsigned short* __restrict__ idxb,
    const int* __restrict__ Mb, float* __restrict__ out)
{
  __shared__ float obuf[2][NSEQ];
  __shared__ float qsh[2][64];

  int bid = blockIdx.x;
  int x = bid & 7;            // batch == XCD
  int u = bid >> 3;           // 0..3071
  int h = u >> 9;             // head 0..5
  int pp = u & 511;           // pair within batch
  int r0 = (x << 10) + (pp << 1), r1 = r0 + 1;
  int lane = threadIdx.x;

  size_t headoff = (size_t)(x * NHEAD + h) * NSEQ;
  int n0 = r0 & 1023;
  qsh[0][lane] = qb2[(headoff + n0) * 64 + lane];
  qsh[1][lane] = qb2[(headoff + n0 + 1) * 64 + lane];

  int M0 = Mb[r0], M1 = Mb[r1];
  const unsigned short* i0p = idxb + (size_t)r0 * IDXCAP;
  const unsigned short* i1p = idxb + (size_t)r1 * IDXCAP;
  const unsigned short* kh = kb2 + headoff * 64;
  const float scale = 0.05103103630798288f;    // 1/sqrt(384)
  float* orow0 = out + (size_t)r0 * (NHEAD * NSEQ) + h * NSEQ;
  float* orow1 = out + (size_t)r1 * (NHEAD * NSEQ) + h * NSEQ;
  float4 zf = make_float4(0.f, 0.f, 0.f, 0.f);

  // pre-zero both staging rows (no downstream dependency until scatter)
  #pragma unroll
  for (int v = 0; v < 4; ++v){
    ((float4*)obuf[0])[v * 64 + lane] = zf;
    ((float4*)obuf[1])[v * 64 + lane] = zf;
  }

  if (M0 <= 128 && M1 <= 128){
    // ---- fast path: 1-2 indices per lane per row, all in registers ----
    int idA0 = i0p[lane];
    int idB0 = i1p[lane];
    bool aA0 = lane < M0, aB0 = lane < M1;
    float zA0 = dotqk(kh + (size_t)idA0 * 64, qsh[0]) * scale;
    float zB0 = dotqk(kh + (size_t)idB0 * 64, qsh[1]) * scale;
    float zA1 = 0.f, zB1 = 0.f;
    int idA1 = 0, idB1 = 0;
    bool aA1 = false, aB1 = false;
    if (M0 > 64){
      idA1 = i0p[64 + lane];
      aA1 = (64 + lane) < M0;
      zA1 = dotqk(kh + (size_t)idA1 * 64, qsh[0]) * scale;
    }
    if (M1 > 64){
      idB1 = i1p[64 + lane];
      aB1 = (64 + lane) < M1;
      zB1 = dotqk(kh + (size_t)idB1 * 64, qsh[1]) * scale;
    }
    // Michelot fixed point: tau = (sum_{z>tau} z - 1)/|{z>tau}|
    float s0 = (aA0 ? zA0 : 0.f) + (aA1 ? zA1 : 0.f);
    float c0 = (aA0 ? 1.f : 0.f) + (aA1 ? 1.f : 0.f);
    float s1 = (aB0 ? zB0 : 0.f) + (aB1 ? zB1 : 0.f);
    float c1 = (aB0 ? 1.f : 0.f) + (aB1 ? 1.f : 0.f);
    red4(s0, c0, s1, c1);
    float tau0 = (s0 - 1.f) / c0, tau1 = (s1 - 1.f) / c1;
    float p0 = c0, p1 = c1;
    #pragma unroll 1
    for (int it = 0; it < 32; ++it){
      bool iA0 = aA0 && zA0 > tau0, iA1 = aA1 && zA1 > tau0;
      bool iB0 = aB0 && zB0 > tau1, iB1 = aB1 && zB1 > tau1;
      s0 = (iA0 ? zA0 : 0.f) + (iA1 ? zA1 : 0.f);
      c0 = (iA0 ? 1.f : 0.f) + (iA1 ? 1.f : 0.f);
      s1 = (iB0 ? zB0 : 0.f) + (iB1 ? zB1 : 0.f);
      c1 = (iB0 ? 1.f : 0.f) + (iB1 ? 1.f : 0.f);
      red4(s0, c0, s1, c1);
      bool stable = (c0 == p0) && (c1 == p1);
      tau0 = (s0 - 1.f) / c0; tau1 = (s1 - 1.f) / c1;
      p0 = c0; p1 = c1;
      if (stable) break;
    }
    // scatter both rows, then write out coalesced (L2 assembles full lines)
    if (aA0){ float q = zA0 - tau0; if (q > 0.f) obuf[0][idA0] = q; }
    if (aA1){ float q = zA1 - tau0; if (q > 0.f) obuf[0][idA1] = q; }
    if (aB0){ float q = zB0 - tau1; if (q > 0.f) obuf[1][idB0] = q; }
    if (aB1){ float q = zB1 - tau1; if (q > 0.f) obuf[1][idB1] = q; }
    #pragma unroll
    for (int v = 0; v < 4; ++v){
      float4 w0 = ((const float4*)obuf[0])[v * 64 + lane];
      float4 w1 = ((const float4*)obuf[1])[v * 64 + lane];
      ((float4*)orow0)[v * 64 + lane] = w0;
      ((float4*)orow1)[v * 64 + lane] = w1;
    }
  } else {
    // ---- generic fallback (M>128, ~never): z staged in obuf row ----
    #pragma unroll 1
    for (int rr = 0; rr < 2; ++rr){
      int M = rr ? M1 : M0;
      const unsigned short* ip = rr ? i1p : i0p;
      const float* qr = qsh[rr];
      float* orow = rr ? orow1 : orow0;
      float* ob = obuf[0];
      #pragma unroll 1
      for (int j0 = 0; j0 < M; j0 += 64){
        int jj = j0 + lane;
        if (jj < M){
          int idx = ip[jj];
          ob[jj] = dotqk(kh + (size_t)idx * 64, qr) * scale;
        }
      }
      float s = 0.f, c = 0.f;
      for (int jj = lane; jj < M; jj += 64){ s += ob[jj]; c += 1.f; }
      red2(s, c);
      float tau = (s - 1.f) / c, pn = c;
      #pragma unroll 1
      for (int it = 0; it < 64; ++it){
        s = 0.f; c = 0.f;
        for (int jj = lane; jj < M; jj += 64){
          float z = ob[jj];
          if (z > tau){ s += z; c += 1.f; }
        }
        red2(s, c);
        if (c == pn) break;
        tau = (s - 1.f) / c; pn = c;
      }
      #pragma unroll
      for (int v = 0; v < 4; ++v) ((float4*)orow)[v * 64 + lane] = zf;
      asm volatile("s_waitcnt vmcnt(0)" ::: "memory");
      for (int jj = lane; jj < M; jj += 64){
        float q = ob[jj] - tau;
        int idx = ip[jj];
        if (q > 0.f) orow[idx] = q;
      }
    }
  }
}

extern "C" void kernel_launch(void* const* d_in, const int* in_sizes, int n_in,
                              void* d_out, int out_size, void* d_ws, size_t ws_size,
                              hipStream_t stream) {
  const float* Q  = (const float*)d_in[0];
  const float* V  = (const float*)d_in[1];
  const float* A  = (const float*)d_in[2];
  const float* WQ = (const float*)d_in[3];
  const float* bQ = (const float*)d_in[4];
  const float* WK = (const float*)d_in[5];
  const float* bK = (const float*)d_in[6];
  float* out = (float*)d_out;

  char* ws = (char*)d_ws;
  float*          qb2  = (float*)ws;                                   // 12.58 MB f32 head-major
  unsigned short* kb2  = (unsigned short*)(ws + (size_t)12582912);     //  6.29 MB bf16 head-major
  unsigned short* wqt  = (unsigned short*)(ws + (size_t)18874368);
  unsigned short* wkt  = wqt + 98304;
  unsigned short* idxb = (unsigned short*)(ws + (size_t)19267584);     //  4.19 MB
  int*            Mb   = (int*)(ws + (size_t)23461888);                //  32 KB
  (void)in_sizes; (void)n_in; (void)out_size; (void)ws_size;

  conv_w_kernel<<<768, 256, 0, stream>>>(WQ, WK, wqt, wkt);
  compact_kernel<<<2048, 256, 0, stream>>>(A, idxb, Mb);
  proj2_kernel<<<dim3(128, 4, 2), 256, 0, stream>>>(Q, V, wqt, wkt, bQ, bK, qb2, kb2);
  attn_kernel<<<24576, 64, 0, stream>>>(qb2, kb2, idxb, Mb, out);
}

// Round 9
// 122.310 us; speedup vs baseline: 1.7893x; 1.1771x over previous
//
#include <hip/hip_runtime.h>
#include <hip/hip_bf16.h>
#include <stdint.h>

#define DIMK 256
#define DIMV 384
#define NSEQ 1024
#define NHEAD 6

typedef __attribute__((ext_vector_type(8))) short short8;
typedef __attribute__((ext_vector_type(4))) float floatx4;

__device__ __forceinline__ unsigned short f2b(float f){
  unsigned int x = __float_as_uint(f);
  return (unsigned short)((x + 0x7fffu + ((x >> 16) & 1u)) >> 16);
}
__device__ __forceinline__ unsigned int pack2(float a, float b){
  return (unsigned int)f2b(a) | ((unsigned int)f2b(b) << 16);
}
__device__ __forceinline__ float blo(unsigned int u){ return __uint_as_float(u << 16); }

// transpose + convert: W [256][384] f32 -> Wt [384][256] bf16 (both weights)
__global__ void conv_w_kernel(const float* __restrict__ WQ, const float* __restrict__ WK,
                              unsigned short* __restrict__ wqt, unsigned short* __restrict__ wkt){
  int i = blockIdx.x * 256 + threadIdx.x;
  const float* W; unsigned short* O; int idx;
  if (i < 98304){ W = WQ; O = wqt; idx = i; }
  else          { W = WK; O = wkt; idx = i - 98304; }
  int n = idx >> 8;
  int k = idx & 255;
  O[idx] = f2b(W[(size_t)k * 384 + n]);
}

// A -> row bitmask: bm[r][c] = ballot of A[r][c*64 + lane] > 0.5  (16 u64 per row)
__global__ __launch_bounds__(256) void maskbits_kernel(const float* __restrict__ A,
    unsigned long long* __restrict__ bm){
  int r = blockIdx.x * 4 + (threadIdx.x >> 6);
  int lane = threadIdx.x & 63;
  const float* arow = A + (size_t)r * NSEQ;
  unsigned long long myw = 0;
  #pragma unroll
  for (int c = 0; c < 16; ++c){
    unsigned long long m = __ballot(arow[c * 64 + lane] > 0.5f);
    if (lane == c) myw = m;
  }
  if (lane < 16) bm[(size_t)r * 16 + lane] = myw;
}

// Merged projections -> MFMA-fragment-major layouts.
// frag coords for value at (seq-pos n, feature d, slice=b*6+h):
//   dst = (((slice*2 + (d>>5))*64 + (n>>4))*64 + ((d>>3)&3)*16 + (n&15))*8 + (d&7)
// z=0: q -> qhi + qlo (bf16 hi/lo split)    z=1: k -> kf (bf16)
__global__ __launch_bounds__(256) void proj2_kernel(
    const float* __restrict__ Q, const float* __restrict__ V,
    const unsigned short* __restrict__ wqt, const unsigned short* __restrict__ wkt,
    const float* __restrict__ bQ, const float* __restrict__ bK,
    unsigned short* __restrict__ qhi, unsigned short* __restrict__ qlo,
    unsigned short* __restrict__ kf)
{
  __shared__ uint4 lA[512];
  __shared__ uint4 lB[864];
  int which = blockIdx.z;
  const float* X = which ? V : Q;
  const unsigned short* Wt = which ? wkt : wqt;
  const float* bias = which ? bK : bQ;

  int t = threadIdx.x;
  int lane = t & 63, wave = t >> 6;
  int wm = wave >> 1, wn = wave & 1;
  int rb = blockIdx.x * 64;
  int nb = blockIdx.y * 96;
  floatx4 acc[2][3];
  #pragma unroll
  for (int mi = 0; mi < 2; ++mi)
    #pragma unroll
    for (int ni = 0; ni < 3; ++ni) acc[mi][ni] = (floatx4){0.f, 0.f, 0.f, 0.f};

  for (int it = 0; it < 4; ++it){
    int k0 = it * 64;
    #pragma unroll
    for (int i = 0; i < 2; ++i){
      int c = t + i * 256;
      int kc = c >> 6, row = c & 63;
      const float* src = X + (size_t)(rb + row) * DIMK + k0 + kc * 8;
      float4 f0 = *(const float4*)src;
      float4 f1 = *(const float4*)(src + 4);
      uint4 w;
      w.x = pack2(f0.x, f0.y); w.y = pack2(f0.z, f0.w);
      w.z = pack2(f1.x, f1.y); w.w = pack2(f1.z, f1.w);
      lA[c] = w;
    }
    #pragma unroll
    for (int i = 0; i < 3; ++i){
      int c = t + i * 256;
      int n = c >> 3, kc = c & 7;
      uint4 v = *(const uint4*)(Wt + (size_t)(nb + n) * DIMK + k0 + kc * 8);
      lB[n * 9 + kc] = v;
    }
    __syncthreads();
    #pragma unroll
    for (int kk = 0; kk < 2; ++kk){
      int kc  = kk * 4 + (lane >> 4);
      int r16 = lane & 15;
      short8 af[2], bf[3];
      #pragma unroll
      for (int mi = 0; mi < 2; ++mi)
        af[mi] = *(const short8*)&lA[kc * 64 + wm * 32 + mi * 16 + r16];
      #pragma unroll
      for (int ni = 0; ni < 3; ++ni)
        bf[ni] = *(const short8*)&lB[(wn * 48 + ni * 16 + r16) * 9 + kc];
      #pragma unroll
      for (int mi = 0; mi < 2; ++mi)
        #pragma unroll
        for (int ni = 0; ni < 3; ++ni)
          acc[mi][ni] = __builtin_amdgcn_mfma_f32_16x16x32_bf16(af[mi], bf[ni], acc[mi][ni], 0, 0, 0);
    }
    __syncthreads();
  }
  int r16 = lane & 15, rq = lane >> 4;
  #pragma unroll
  for (int ni = 0; ni < 3; ++ni){
    int col = nb + wn * 48 + ni * 16 + r16;
    float bv = bias[col];
    int h = col >> 6, d = col & 63;
    #pragma unroll
    for (int mi = 0; mi < 2; ++mi){
      #pragma unroll
      for (int q = 0; q < 4; ++q){
        int row = rb + wm * 32 + mi * 16 + rq * 4 + q;
        int bb = row >> 10, n = row & 1023;
        int slice = bb * NHEAD + h;
        size_t dst = ((((size_t)slice * 2 + (d >> 5)) * 64 + (n >> 4)) * 64
                      + ((d >> 3) & 3) * 16 + (n & 15)) * 8 + (d & 7);
        float v = acc[mi][ni][q] + bv;
        if (which){
          kf[dst] = f2b(v);
        } else {
          unsigned short hi_ = f2b(v);
          qhi[dst] = hi_;
          qlo[dst] = f2b(v - blo((unsigned int)hi_));
        }
      }
    }
  }
}

__device__ __forceinline__ void red4(float& a, float& b, float& c, float& d){
  #pragma unroll
  for (int o = 1; o < 64; o <<= 1){
    a += __shfl_xor(a, o); b += __shfl_xor(b, o);
    c += __shfl_xor(c, o); d += __shfl_xor(d, o);
  }
}

// Dense MFMA attn: workgroup = 8 waves, 16 rows x 1024 cols of one (b,h).
// Fragment loads fully coalesced from frag-major buffers; logits -> 64KB
// XOR-swizzled LDS; one barrier; per-wave register Michelot on 2 full rows
// (mask via wave-uniform u64 loads); dense coalesced stores (masked cols
// are -1e10 -> 0 automatically; every output element written exactly once).
__global__ __launch_bounds__(512) void attn_kernel(
    const unsigned short* __restrict__ qhi, const unsigned short* __restrict__ qlo,
    const unsigned short* __restrict__ kf, const unsigned long long* __restrict__ bm,
    float* __restrict__ out)
{
  __shared__ float zbuf[16][1024];

  int bid = blockIdx.x;
  int x = bid & 7;            // batch == XCD
  int u = bid >> 3;           // 0..383
  int h = u >> 6;             // head
  int rb = u & 63;            // 16-row block
  int tid = threadIdx.x;
  int lane = tid & 63, w = tid >> 6;
  int slice = x * NHEAD + h;
  int r0 = rb << 4;

  const short8* qh8 = (const short8*)qhi;
  const short8* ql8 = (const short8*)qlo;
  const short8* kf8 = (const short8*)kf;
  size_t ab0 = (((size_t)slice * 2 + 0) * 64 + rb) * 64 + lane;
  size_t ab1 = (((size_t)slice * 2 + 1) * 64 + rb) * 64 + lane;
  short8 ah0 = qh8[ab0], al0 = ql8[ab0];
  short8 ah1 = qh8[ab1], al1 = ql8[ab1];

  #pragma unroll
  for (int i = 0; i < 8; ++i){
    int tt = (w << 3) + i;
    short8 b0 = kf8[(((size_t)slice * 2 + 0) * 64 + tt) * 64 + lane];
    short8 b1 = kf8[(((size_t)slice * 2 + 1) * 64 + tt) * 64 + lane];
    floatx4 a = (floatx4){0.f, 0.f, 0.f, 0.f};
    a = __builtin_amdgcn_mfma_f32_16x16x32_bf16(al0, b0, a, 0, 0, 0);
    a = __builtin_amdgcn_mfma_f32_16x16x32_bf16(ah0, b0, a, 0, 0, 0);
    a = __builtin_amdgcn_mfma_f32_16x16x32_bf16(al1, b1, a, 0, 0, 0);
    a = __builtin_amdgcn_mfma_f32_16x16x32_bf16(ah1, b1, a, 0, 0, 0);
    int colb = (w << 7) + (i << 4) + (lane & 15);
    #pragma unroll
    for (int reg = 0; reg < 4; ++reg){
      int rowz = ((lane >> 4) << 2) + reg;         // C/D: col=lane&15, row=(lane>>4)*4+reg
      zbuf[rowz][colb ^ ((rowz & 4) << 2)] = a[reg];
    }
  }
  __syncthreads();

  const float scale = 0.05103103630798288f;        // 1/sqrt(384)
  int row0 = w * 2, row1 = w * 2 + 1;
  const unsigned long long* bm0 = bm + ((size_t)(x << 10) + r0 + row0) * 16;
  const unsigned long long* bm1 = bm + ((size_t)(x << 10) + r0 + row1) * 16;
  int sw0 = (row0 & 4) << 2, sw1 = (row1 & 4) << 2;
  float z0[16], z1[16];
  #pragma unroll
  for (int c = 0; c < 16; ++c){
    bool on0 = (bm0[c] >> lane) & 1;
    bool on1 = (bm1[c] >> lane) & 1;
    int col = (c << 6) + lane;
    z0[c] = on0 ? zbuf[row0][col ^ sw0] * scale : -1e10f;
    z1[c] = on1 ? zbuf[row1][col ^ sw1] * scale : -1e10f;
  }
  // Michelot fixed point: tau = (sum_{z>tau} z - 1)/|{z>tau}|; init support =
  // all unmasked (tau=-1e9 excludes the -1e10 masked entries).
  float tau0 = -1e9f, tau1 = -1e9f, p0 = -1.f, p1 = -1.f;
  #pragma unroll 1
  for (int it = 0; it < 32; ++it){
    float s0 = 0.f, c0 = 0.f, s1 = 0.f, c1 = 0.f;
    #pragma unroll
    for (int c = 0; c < 16; ++c){
      if (z0[c] > tau0){ s0 += z0[c]; c0 += 1.f; }
      if (z1[c] > tau1){ s1 += z1[c]; c1 += 1.f; }
    }
    red4(s0, c0, s1, c1);
    bool stable = (c0 == p0) && (c1 == p1);
    tau0 = (s0 - 1.f) / c0; tau1 = (s1 - 1.f) / c1;
    p0 = c0; p1 = c1;
    if (stable) break;
  }
  float* o0 = out + ((size_t)((x << 10) + r0 + row0) * NHEAD + h) * NSEQ;
  float* o1 = out + ((size_t)((x << 10) + r0 + row1) * NHEAD + h) * NSEQ;
  #pragma unroll
  for (int c = 0; c < 16; ++c){
    o0[(c << 6) + lane] = fmaxf(z0[c] - tau0, 0.f);
    o1[(c << 6) + lane] = fmaxf(z1[c] - tau1, 0.f);
  }
}

extern "C" void kernel_launch(void* const* d_in, const int* in_sizes, int n_in,
                              void* d_out, int out_size, void* d_ws, size_t ws_size,
                              hipStream_t stream) {
  const float* Q  = (const float*)d_in[0];
  const float* V  = (const float*)d_in[1];
  const float* A  = (const float*)d_in[2];
  const float* WQ = (const float*)d_in[3];
  const float* bQ = (const float*)d_in[4];
  const float* WK = (const float*)d_in[5];
  const float* bK = (const float*)d_in[6];
  float* out = (float*)d_out;

  char* ws = (char*)d_ws;
  unsigned short*     qhi = (unsigned short*)ws;                          // 6.29 MB
  unsigned short*     qlo = (unsigned short*)(ws + (size_t)6291456);      // 6.29 MB
  unsigned short*     kf  = (unsigned short*)(ws + (size_t)12582912);     // 6.29 MB
  unsigned short*     wqt = (unsigned short*)(ws + (size_t)18874368);     // 0.20 MB
  unsigned short*     wkt = (unsigned short*)(ws + (size_t)19070976);     // 0.20 MB
  unsigned long long* bm  = (unsigned long long*)(ws + (size_t)19267584); // 1.05 MB
  (void)in_sizes; (void)n_in; (void)out_size; (void)ws_size;

  conv_w_kernel<<<768, 256, 0, stream>>>(WQ, WK, wqt, wkt);
  maskbits_kernel<<<2048, 256, 0, stream>>>(A, bm);
  proj2_kernel<<<dim3(128, 4, 2), 256, 0, stream>>>(Q, V, wqt, wkt, bQ, bK, qhi, qlo, kf);
  attn_kernel<<<3072, 512, 0, stream>>>(qhi, qlo, kf, bm, out);
}

// Round 10
// 107.815 us; speedup vs baseline: 2.0299x; 1.1344x over previous
//
#include <hip/hip_runtime.h>
#include <hip/hip_bf16.h>
#include <stdint.h>

#define DIMK 256
#define DIMV 384
#define NSEQ 1024
#define NHEAD 6
#define ZCAP 192

typedef __attribute__((ext_vector_type(8))) short short8;
typedef __attribute__((ext_vector_type(4))) float floatx4;

__device__ __forceinline__ unsigned short f2b(float f){
  unsigned int x = __float_as_uint(f);
  return (unsigned short)((x + 0x7fffu + ((x >> 16) & 1u)) >> 16);
}
__device__ __forceinline__ unsigned int pack2(float a, float b){
  return (unsigned int)f2b(a) | ((unsigned int)f2b(b) << 16);
}
__device__ __forceinline__ float blo(unsigned int u){ return __uint_as_float(u << 16); }

// transpose + convert: W [256][384] f32 -> Wt [384][256] bf16 (both weights)
__global__ void conv_w_kernel(const float* __restrict__ WQ, const float* __restrict__ WK,
                              unsigned short* __restrict__ wqt, unsigned short* __restrict__ wkt){
  int i = blockIdx.x * 256 + threadIdx.x;
  const float* W; unsigned short* O; int idx;
  if (i < 98304){ W = WQ; O = wqt; idx = i; }
  else          { W = WK; O = wkt; idx = i - 98304; }
  int n = idx >> 8;
  int k = idx & 255;
  O[idx] = f2b(W[(size_t)k * 384 + n]);
}

// A -> row bitmask (16 u64/row) + exclusive word-prefix popcounts (16 u16/row)
__global__ __launch_bounds__(256) void maskbits_kernel(const float* __restrict__ A,
    unsigned long long* __restrict__ bm, unsigned short* __restrict__ bmp){
  int r = blockIdx.x * 4 + (threadIdx.x >> 6);
  int lane = threadIdx.x & 63;
  const float* arow = A + (size_t)r * NSEQ;
  unsigned long long myw = 0;
  #pragma unroll
  for (int c = 0; c < 16; ++c){
    unsigned long long m = __ballot(arow[c * 64 + lane] > 0.5f);
    if (lane == c) myw = m;
  }
  int own = (lane < 16) ? __popcll(myw) : 0;
  int inc = own;
  #pragma unroll
  for (int o = 1; o < 16; o <<= 1){
    int t = __shfl_up(inc, o, 16);
    if ((lane & 15) >= o) inc += t;
  }
  if (lane < 16){
    bm [(size_t)r * 16 + lane] = myw;
    bmp[(size_t)r * 16 + lane] = (unsigned short)(inc - own);
  }
}

// Merged projections -> MFMA-fragment-major layouts.
// frag coords for value at (seq-pos n, feature d, slice=b*6+h):
//   dst = (((slice*2 + (d>>5))*64 + (n>>4))*64 + ((d>>3)&3)*16 + (n&15))*8 + (d&7)
// z=0: q -> qhi + qlo (bf16 hi/lo split)    z=1: k -> kf (bf16)
__global__ __launch_bounds__(256) void proj2_kernel(
    const float* __restrict__ Q, const float* __restrict__ V,
    const unsigned short* __restrict__ wqt, const unsigned short* __restrict__ wkt,
    const float* __restrict__ bQ, const float* __restrict__ bK,
    unsigned short* __restrict__ qhi, unsigned short* __restrict__ qlo,
    unsigned short* __restrict__ kf)
{
  __shared__ uint4 lA[512];
  __shared__ uint4 lB[864];
  int which = blockIdx.z;
  const float* X = which ? V : Q;
  const unsigned short* Wt = which ? wkt : wqt;
  const float* bias = which ? bK : bQ;

  int t = threadIdx.x;
  int lane = t & 63, wave = t >> 6;
  int wm = wave >> 1, wn = wave & 1;
  int rb = blockIdx.x * 64;
  int nb = blockIdx.y * 96;
  floatx4 acc[2][3];
  #pragma unroll
  for (int mi = 0; mi < 2; ++mi)
    #pragma unroll
    for (int ni = 0; ni < 3; ++ni) acc[mi][ni] = (floatx4){0.f, 0.f, 0.f, 0.f};

  for (int it = 0; it < 4; ++it){
    int k0 = it * 64;
    #pragma unroll
    for (int i = 0; i < 2; ++i){
      int c = t + i * 256;
      int kc = c >> 6, row = c & 63;
      const float* src = X + (size_t)(rb + row) * DIMK + k0 + kc * 8;
      float4 f0 = *(const float4*)src;
      float4 f1 = *(const float4*)(src + 4);
      uint4 w;
      w.x = pack2(f0.x, f0.y); w.y = pack2(f0.z, f0.w);
      w.z = pack2(f1.x, f1.y); w.w = pack2(f1.z, f1.w);
      lA[c] = w;
    }
    #pragma unroll
    for (int i = 0; i < 3; ++i){
      int c = t + i * 256;
      int n = c >> 3, kc = c & 7;
      uint4 v = *(const uint4*)(Wt + (size_t)(nb + n) * DIMK + k0 + kc * 8);
      lB[n * 9 + kc] = v;
    }
    __syncthreads();
    #pragma unroll
    for (int kk = 0; kk < 2; ++kk){
      int kc  = kk * 4 + (lane >> 4);
      int r16 = lane & 15;
      short8 af[2], bf[3];
      #pragma unroll
      for (int mi = 0; mi < 2; ++mi)
        af[mi] = *(const short8*)&lA[kc * 64 + wm * 32 + mi * 16 + r16];
      #pragma unroll
      for (int ni = 0; ni < 3; ++ni)
        bf[ni] = *(const short8*)&lB[(wn * 48 + ni * 16 + r16) * 9 + kc];
      #pragma unroll
      for (int mi = 0; mi < 2; ++mi)
        #pragma unroll
        for (int ni = 0; ni < 3; ++ni)
          acc[mi][ni] = __builtin_amdgcn_mfma_f32_16x16x32_bf16(af[mi], bf[ni], acc[mi][ni], 0, 0, 0);
    }
    __syncthreads();
  }
  int r16 = lane & 15, rq = lane >> 4;
  #pragma unroll
  for (int ni = 0; ni < 3; ++ni){
    int col = nb + wn * 48 + ni * 16 + r16;
    float bv = bias[col];
    int h = col >> 6, d = col & 63;
    #pragma unroll
    for (int mi = 0; mi < 2; ++mi){
      #pragma unroll
      for (int q = 0; q < 4; ++q){
        int row = rb + wm * 32 + mi * 16 + rq * 4 + q;
        int bb = row >> 10, n = row & 1023;
        int slice = bb * NHEAD + h;
        size_t dst = ((((size_t)slice * 2 + (d >> 5)) * 64 + (n >> 4)) * 64
                      + ((d >> 3) & 3) * 16 + (n & 15)) * 8 + (d & 7);
        float v = acc[mi][ni][q] + bv;
        if (which){
          kf[dst] = f2b(v);
        } else {
          unsigned short hi_ = f2b(v);
          qhi[dst] = hi_;
          qlo[dst] = f2b(v - blo((unsigned int)hi_));
        }
      }
    }
  }
}

__device__ __forceinline__ void red4(float& a, float& b, float& c, float& d){
  #pragma unroll
  for (int o = 1; o < 64; o <<= 1){
    a += __shfl_xor(a, o); b += __shfl_xor(b, o);
    c += __shfl_xor(c, o); d += __shfl_xor(d, o);
  }
}

// Dense MFMA attn with COMPACTED logits: workgroup = 8 waves, 16 rows x 1024
// cols of one (b,h). MFMA epilogue scatters only masked logits into
// zlds[row][rank] (rank = prefix-popcount of the row bitmap -> ordered,
// race-free). Michelot on compacted values (no sentinels); dense output
// reconstructed by rank lookup. LDS ~15 KB -> wave-cap occupancy.
__global__ __launch_bounds__(512) void attn_kernel(
    const unsigned short* __restrict__ qhi, const unsigned short* __restrict__ qlo,
    const unsigned short* __restrict__ kf, const unsigned long long* __restrict__ bm,
    const unsigned short* __restrict__ bmp, float* __restrict__ out)
{
  __shared__ unsigned long long mw[16][16];
  __shared__ unsigned short    mp[16][16];
  __shared__ float             zlds[16][ZCAP];

  int bid = blockIdx.x;
  int x = bid & 7;            // batch == XCD
  int u = bid >> 3;           // 0..383
  int h = u >> 6;             // head
  int rb = u & 63;            // 16-row block
  int tid = threadIdx.x;
  int lane = tid & 63, w = tid >> 6;
  int slice = x * NHEAD + h;
  int rowbase = (x << 10) + (rb << 4);

  // cooperative load of the block's mask words + prefixes (256 of 512 thr)
  if (tid < 256){
    int rr = tid >> 4, ww = tid & 15;
    mw[rr][ww] = bm [((size_t)(rowbase + rr)) * 16 + ww];
    mp[rr][ww] = bmp[((size_t)(rowbase + rr)) * 16 + ww];
  }

  const short8* qh8 = (const short8*)qhi;
  const short8* ql8 = (const short8*)qlo;
  const short8* kf8 = (const short8*)kf;
  size_t ab0 = (((size_t)slice * 2 + 0) * 64 + rb) * 64 + lane;
  size_t ab1 = (((size_t)slice * 2 + 1) * 64 + rb) * 64 + lane;
  short8 ah0 = qh8[ab0], al0 = ql8[ab0];
  short8 ah1 = qh8[ab1], al1 = ql8[ab1];
  __syncthreads();

  #pragma unroll
  for (int i = 0; i < 8; ++i){
    int tt = (w << 3) + i;
    short8 b0 = kf8[(((size_t)slice * 2 + 0) * 64 + tt) * 64 + lane];
    short8 b1 = kf8[(((size_t)slice * 2 + 1) * 64 + tt) * 64 + lane];
    floatx4 a = (floatx4){0.f, 0.f, 0.f, 0.f};
    a = __builtin_amdgcn_mfma_f32_16x16x32_bf16(al0, b0, a, 0, 0, 0);
    a = __builtin_amdgcn_mfma_f32_16x16x32_bf16(ah0, b0, a, 0, 0, 0);
    a = __builtin_amdgcn_mfma_f32_16x16x32_bf16(al1, b1, a, 0, 0, 0);
    a = __builtin_amdgcn_mfma_f32_16x16x32_bf16(ah1, b1, a, 0, 0, 0);
    int colb = (w << 7) + (i << 4) + (lane & 15);
    int cw = colb >> 6, cb = colb & 63;
    unsigned long long below = (1ull << cb) - 1ull;
    #pragma unroll
    for (int reg = 0; reg < 4; ++reg){
      int rowz = ((lane >> 4) << 2) + reg;       // verified mapping (r8/r9 passed)
      unsigned long long word = mw[rowz][cw];
      if ((word >> cb) & 1){
        int rank = (int)mp[rowz][cw] + __popcll(word & below);
        if (rank < ZCAP) zlds[rowz][rank] = a[reg];
      }
    }
  }
  __syncthreads();

  const float scale = 0.05103103630798288f;      // 1/sqrt(384)
  int row0 = w * 2, row1 = w * 2 + 1;
  int M0 = (int)mp[row0][15] + __popcll(mw[row0][15]);
  int M1 = (int)mp[row1][15] + __popcll(mw[row1][15]);

  // register chunks (cap 192 = 3 x 64); typical M ~52 -> only chunk 0 live
  float z0a = (lane < M0)       ? zlds[row0][lane]       * scale : 0.f;
  float z1a = (lane < M1)       ? zlds[row1][lane]       * scale : 0.f;
  float z0b = (64 + lane < M0)  ? zlds[row0][64 + lane]  * scale : 0.f;
  float z1b = (64 + lane < M1)  ? zlds[row1][64 + lane]  * scale : 0.f;
  float z0c = (128 + lane < M0) ? zlds[row0][128 + lane] * scale : 0.f;
  float z1c = (128 + lane < M1) ? zlds[row1][128 + lane] * scale : 0.f;
  bool a0 = lane < M0, b0_ = 64 + lane < M0, c0_ = 128 + lane < M0;
  bool a1 = lane < M1, b1_ = 64 + lane < M1, c1_ = 128 + lane < M1;

  // Michelot fixed point: tau = (sum_{z>tau} z - 1)/|{z>tau}| on compacted z
  float s0 = (a0 ? z0a : 0.f) + (b0_ ? z0b : 0.f) + (c0_ ? z0c : 0.f);
  float n0 = (a0 ? 1.f : 0.f) + (b0_ ? 1.f : 0.f) + (c0_ ? 1.f : 0.f);
  float s1 = (a1 ? z1a : 0.f) + (b1_ ? z1b : 0.f) + (c1_ ? z1c : 0.f);
  float n1 = (a1 ? 1.f : 0.f) + (b1_ ? 1.f : 0.f) + (c1_ ? 1.f : 0.f);
  red4(s0, n0, s1, n1);
  float tau0 = (s0 - 1.f) / n0, tau1 = (s1 - 1.f) / n1;
  float p0 = n0, p1 = n1;
  #pragma unroll 1
  for (int it = 0; it < 32; ++it){
    bool i0a = a0 && z0a > tau0, i0b = b0_ && z0b > tau0, i0c = c0_ && z0c > tau0;
    bool i1a = a1 && z1a > tau1, i1b = b1_ && z1b > tau1, i1c = c1_ && z1c > tau1;
    s0 = (i0a ? z0a : 0.f) + (i0b ? z0b : 0.f) + (i0c ? z0c : 0.f);
    n0 = (i0a ? 1.f : 0.f) + (i0b ? 1.f : 0.f) + (i0c ? 1.f : 0.f);
    s1 = (i1a ? z1a : 0.f) + (i1b ? z1b : 0.f) + (i1c ? z1c : 0.f);
    n1 = (i1a ? 1.f : 0.f) + (i1b ? 1.f : 0.f) + (i1c ? 1.f : 0.f);
    red4(s0, n0, s1, n1);
    bool stable = (n0 == p0) && (n1 == p1);
    tau0 = (s0 - 1.f) / n0; tau1 = (s1 - 1.f) / n1;
    p0 = n0; p1 = n1;
    if (stable) break;
  }

  // dense output by rank lookup: bit ? max(z[rank]-tau, 0) : 0
  unsigned long long lmask = (1ull << lane) - 1ull;
  float* o0 = out + ((size_t)(rowbase + row0) * NHEAD + h) * NSEQ;
  float* o1 = out + ((size_t)(rowbase + row1) * NHEAD + h) * NSEQ;
  #pragma unroll
  for (int c = 0; c < 16; ++c){
    unsigned long long w0 = mw[row0][c], w1 = mw[row1][c];
    float v0 = 0.f, v1 = 0.f;
    if ((w0 >> lane) & 1){
      int rank = (int)mp[row0][c] + __popcll(w0 & lmask);
      if (rank < ZCAP) v0 = fmaxf(zlds[row0][rank] * scale - tau0, 0.f);
    }
    if ((w1 >> lane) & 1){
      int rank = (int)mp[row1][c] + __popcll(w1 & lmask);
      if (rank < ZCAP) v1 = fmaxf(zlds[row1][rank] * scale - tau1, 0.f);
    }
    o0[(c << 6) + lane] = v0;
    o1[(c << 6) + lane] = v1;
  }
}

extern "C" void kernel_launch(void* const* d_in, const int* in_sizes, int n_in,
                              void* d_out, int out_size, void* d_ws, size_t ws_size,
                              hipStream_t stream) {
  const float* Q  = (const float*)d_in[0];
  const float* V  = (const float*)d_in[1];
  const float* A  = (const float*)d_in[2];
  const float* WQ = (const float*)d_in[3];
  const float* bQ = (const float*)d_in[4];
  const float* WK = (const float*)d_in[5];
  const float* bK = (const float*)d_in[6];
  float* out = (float*)d_out;

  char* ws = (char*)d_ws;
  unsigned short*     qhi = (unsigned short*)ws;                          // 6.29 MB
  unsigned short*     qlo = (unsigned short*)(ws + (size_t)6291456);      // 6.29 MB
  unsigned short*     kf  = (unsigned short*)(ws + (size_t)12582912);     // 6.29 MB
  unsigned short*     wqt = (unsigned short*)(ws + (size_t)18874368);     // 0.20 MB
  unsigned short*     wkt = (unsigned short*)(ws + (size_t)19070976);     // 0.20 MB
  unsigned long long* bm  = (unsigned long long*)(ws + (size_t)19267584); // 1.05 MB
  unsigned short*     bmp = (unsigned short*)(ws + (size_t)20316160);     // 0.26 MB
  (void)in_sizes; (void)n_in; (void)out_size; (void)ws_size;

  conv_w_kernel<<<768, 256, 0, stream>>>(WQ, WK, wqt, wkt);
  maskbits_kernel<<<2048, 256, 0, stream>>>(A, bm, bmp);
  proj2_kernel<<<dim3(128, 4, 2), 256, 0, stream>>>(Q, V, wqt, wkt, bQ, bK, qhi, qlo, kf);
  attn_kernel<<<3072, 512, 0, stream>>>(qhi, qlo, kf, bm, bmp, out);
}

// Round 11
// 97.262 us; speedup vs baseline: 2.2501x; 1.1085x over previous
//
#include <hip/hip_runtime.h>
#include <hip/hip_bf16.h>
#include <stdint.h>

#define DIMK 256
#define DIMV 384
#define NSEQ 1024
#define NHEAD 6
#define ZCAP 192

typedef __attribute__((ext_vector_type(8))) short short8;
typedef __attribute__((ext_vector_type(4))) float floatx4;

__device__ __forceinline__ unsigned short f2b(float f){
  unsigned int x = __float_as_uint(f);
  return (unsigned short)((x + 0x7fffu + ((x >> 16) & 1u)) >> 16);
}
__device__ __forceinline__ unsigned int pack2(float a, float b){
  return (unsigned int)f2b(a) | ((unsigned int)f2b(b) << 16);
}
__device__ __forceinline__ float blo(unsigned int u){ return __uint_as_float(u << 16); }

// Fused independent producers (flat grid, 256 thr):
//   bid < 768 : W transpose+convert -> wqt/wkt bf16 [384][256]
//   bid >= 768: A -> row bitmask (16 u64/row) + exclusive word-prefix popcounts
__global__ __launch_bounds__(256) void prep_kernel(
    const float* __restrict__ WQ, const float* __restrict__ WK,
    unsigned short* __restrict__ wqt, unsigned short* __restrict__ wkt,
    const float* __restrict__ A,
    unsigned long long* __restrict__ bm, unsigned short* __restrict__ bmp)
{
  int bid = blockIdx.x;
  if (bid < 768){
    int i = bid * 256 + threadIdx.x;
    const float* W; unsigned short* O; int idx;
    if (i < 98304){ W = WQ; O = wqt; idx = i; }
    else          { W = WK; O = wkt; idx = i - 98304; }
    int n = idx >> 8;
    int k = idx & 255;
    O[idx] = f2b(W[(size_t)k * 384 + n]);
  } else {
    int r = (bid - 768) * 4 + (threadIdx.x >> 6);
    int lane = threadIdx.x & 63;
    const float* arow = A + (size_t)r * NSEQ;
    unsigned long long myw = 0;
    #pragma unroll
    for (int c = 0; c < 16; ++c){
      unsigned long long m = __ballot(arow[c * 64 + lane] > 0.5f);
      if (lane == c) myw = m;
    }
    int own = (lane < 16) ? __popcll(myw) : 0;
    int inc = own;
    #pragma unroll
    for (int o = 1; o < 16; o <<= 1){
      int t = __shfl_up(inc, o, 16);
      if ((lane & 15) >= o) inc += t;
    }
    if (lane < 16){
      bm [(size_t)r * 16 + lane] = myw;
      bmp[(size_t)r * 16 + lane] = (unsigned short)(inc - own);
    }
  }
}

// Merged projections -> MFMA-fragment-major layouts.
// frag coords for value at (seq-pos n, feature d, slice=b*6+h):
//   dst = (((slice*2 + (d>>5))*64 + (n>>4))*64 + ((d>>3)&3)*16 + (n&15))*8 + (d&7)
// z=0: q -> qhi + qlo (bf16 hi/lo split)    z=1: k -> kf (bf16)
__global__ __launch_bounds__(256) void proj2_kernel(
    const float* __restrict__ Q, const float* __restrict__ V,
    const unsigned short* __restrict__ wqt, const unsigned short* __restrict__ wkt,
    const float* __restrict__ bQ, const float* __restrict__ bK,
    unsigned short* __restrict__ qhi, unsigned short* __restrict__ qlo,
    unsigned short* __restrict__ kf)
{
  __shared__ uint4 lA[512];
  __shared__ uint4 lB[864];
  int which = blockIdx.z;
  const float* X = which ? V : Q;
  const unsigned short* Wt = which ? wkt : wqt;
  const float* bias = which ? bK : bQ;

  int t = threadIdx.x;
  int lane = t & 63, wave = t >> 6;
  int wm = wave >> 1, wn = wave & 1;
  int rb = blockIdx.x * 64;
  int nb = blockIdx.y * 96;
  floatx4 acc[2][3];
  #pragma unroll
  for (int mi = 0; mi < 2; ++mi)
    #pragma unroll
    for (int ni = 0; ni < 3; ++ni) acc[mi][ni] = (floatx4){0.f, 0.f, 0.f, 0.f};

  for (int it = 0; it < 4; ++it){
    int k0 = it * 64;
    #pragma unroll
    for (int i = 0; i < 2; ++i){
      int c = t + i * 256;
      int kc = c >> 6, row = c & 63;
      const float* src = X + (size_t)(rb + row) * DIMK + k0 + kc * 8;
      float4 f0 = *(const float4*)src;
      float4 f1 = *(const float4*)(src + 4);
      uint4 w;
      w.x = pack2(f0.x, f0.y); w.y = pack2(f0.z, f0.w);
      w.z = pack2(f1.x, f1.y); w.w = pack2(f1.z, f1.w);
      lA[c] = w;
    }
    #pragma unroll
    for (int i = 0; i < 3; ++i){
      int c = t + i * 256;
      int n = c >> 3, kc = c & 7;
      uint4 v = *(const uint4*)(Wt + (size_t)(nb + n) * DIMK + k0 + kc * 8);
      lB[n * 9 + kc] = v;
    }
    __syncthreads();
    #pragma unroll
    for (int kk = 0; kk < 2; ++kk){
      int kc  = kk * 4 + (lane >> 4);
      int r16 = lane & 15;
      short8 af[2], bf[3];
      #pragma unroll
      for (int mi = 0; mi < 2; ++mi)
        af[mi] = *(const short8*)&lA[kc * 64 + wm * 32 + mi * 16 + r16];
      #pragma unroll
      for (int ni = 0; ni < 3; ++ni)
        bf[ni] = *(const short8*)&lB[(wn * 48 + ni * 16 + r16) * 9 + kc];
      #pragma unroll
      for (int mi = 0; mi < 2; ++mi)
        #pragma unroll
        for (int ni = 0; ni < 3; ++ni)
          acc[mi][ni] = __builtin_amdgcn_mfma_f32_16x16x32_bf16(af[mi], bf[ni], acc[mi][ni], 0, 0, 0);
    }
    __syncthreads();
  }
  int r16 = lane & 15, rq = lane >> 4;
  #pragma unroll
  for (int ni = 0; ni < 3; ++ni){
    int col = nb + wn * 48 + ni * 16 + r16;
    float bv = bias[col];
    int h = col >> 6, d = col & 63;
    #pragma unroll
    for (int mi = 0; mi < 2; ++mi){
      #pragma unroll
      for (int q = 0; q < 4; ++q){
        int row = rb + wm * 32 + mi * 16 + rq * 4 + q;
        int bb = row >> 10, n = row & 1023;
        int slice = bb * NHEAD + h;
        size_t dst = ((((size_t)slice * 2 + (d >> 5)) * 64 + (n >> 4)) * 64
                      + ((d >> 3) & 3) * 16 + (n & 15)) * 8 + (d & 7);
        float v = acc[mi][ni][q] + bv;
        if (which){
          kf[dst] = f2b(v);
        } else {
          unsigned short hi_ = f2b(v);
          qhi[dst] = hi_;
          qlo[dst] = f2b(v - blo((unsigned int)hi_));
        }
      }
    }
  }
}

__device__ __forceinline__ void red4(float& a, float& b, float& c, float& d){
  #pragma unroll
  for (int o = 1; o < 64; o <<= 1){
    a += __shfl_xor(a, o); b += __shfl_xor(b, o);
    c += __shfl_xor(c, o); d += __shfl_xor(d, o);
  }
}

// Dense MFMA attn with COMPACTED logits (r10 structure) + vectorized dense
// stores: each lane owns 4 consecutive cols per quarter-row -> one mask-word
// read, base popcount, 4-bit walk, one dwordx4 store (1KB dense per instr).
__global__ __launch_bounds__(512) void attn_kernel(
    const unsigned short* __restrict__ qhi, const unsigned short* __restrict__ qlo,
    const unsigned short* __restrict__ kf, const unsigned long long* __restrict__ bm,
    const unsigned short* __restrict__ bmp, float* __restrict__ out)
{
  __shared__ unsigned long long mw[16][16];
  __shared__ unsigned short    mp[16][16];
  __shared__ float             zlds[16][ZCAP + 1];

  int bid = blockIdx.x;
  int x = bid & 7;            // batch == XCD
  int u = bid >> 3;           // 0..383
  int h = u >> 6;             // head
  int rb = u & 63;            // 16-row block
  int tid = threadIdx.x;
  int lane = tid & 63, w = tid >> 6;
  int slice = x * NHEAD + h;
  int rowbase = (x << 10) + (rb << 4);

  // cooperative load of the block's mask words + prefixes (256 of 512 thr)
  if (tid < 256){
    int rr = tid >> 4, ww = tid & 15;
    mw[rr][ww] = bm [((size_t)(rowbase + rr)) * 16 + ww];
    mp[rr][ww] = bmp[((size_t)(rowbase + rr)) * 16 + ww];
  }

  const short8* qh8 = (const short8*)qhi;
  const short8* ql8 = (const short8*)qlo;
  const short8* kf8 = (const short8*)kf;
  size_t ab0 = (((size_t)slice * 2 + 0) * 64 + rb) * 64 + lane;
  size_t ab1 = (((size_t)slice * 2 + 1) * 64 + rb) * 64 + lane;
  short8 ah0 = qh8[ab0], al0 = ql8[ab0];
  short8 ah1 = qh8[ab1], al1 = ql8[ab1];
  __syncthreads();

  #pragma unroll
  for (int i = 0; i < 8; ++i){
    int tt = (w << 3) + i;
    short8 b0 = kf8[(((size_t)slice * 2 + 0) * 64 + tt) * 64 + lane];
    short8 b1 = kf8[(((size_t)slice * 2 + 1) * 64 + tt) * 64 + lane];
    floatx4 a = (floatx4){0.f, 0.f, 0.f, 0.f};
    a = __builtin_amdgcn_mfma_f32_16x16x32_bf16(al0, b0, a, 0, 0, 0);
    a = __builtin_amdgcn_mfma_f32_16x16x32_bf16(ah0, b0, a, 0, 0, 0);
    a = __builtin_amdgcn_mfma_f32_16x16x32_bf16(al1, b1, a, 0, 0, 0);
    a = __builtin_amdgcn_mfma_f32_16x16x32_bf16(ah1, b1, a, 0, 0, 0);
    int colb = (w << 7) + (i << 4) + (lane & 15);
    int cw = colb >> 6, cb = colb & 63;
    unsigned long long below = (1ull << cb) - 1ull;
    #pragma unroll
    for (int reg = 0; reg < 4; ++reg){
      int rowz = ((lane >> 4) << 2) + reg;       // C/D: col=lane&15, row=(lane>>4)*4+reg
      unsigned long long word = mw[rowz][cw];
      if ((word >> cb) & 1){
        int rank = (int)mp[rowz][cw] + __popcll(word & below);
        if (rank < ZCAP) zlds[rowz][rank] = a[reg];
      }
    }
  }
  __syncthreads();

  const float scale = 0.05103103630798288f;      // 1/sqrt(384)
  int row0 = w * 2, row1 = w * 2 + 1;
  int M0 = (int)mp[row0][15] + __popcll(mw[row0][15]);
  int M1 = (int)mp[row1][15] + __popcll(mw[row1][15]);

  // register chunks (cap 192 = 3 x 64); typical M ~52 -> only chunk 0 live
  float z0a = (lane < M0)       ? zlds[row0][lane]       * scale : 0.f;
  float z1a = (lane < M1)       ? zlds[row1][lane]       * scale : 0.f;
  float z0b = (64 + lane < M0)  ? zlds[row0][64 + lane]  * scale : 0.f;
  float z1b = (64 + lane < M1)  ? zlds[row1][64 + lane]  * scale : 0.f;
  float z0c = (128 + lane < M0) ? zlds[row0][128 + lane] * scale : 0.f;
  float z1c = (128 + lane < M1) ? zlds[row1][128 + lane] * scale : 0.f;
  bool a0 = lane < M0, b0_ = 64 + lane < M0, c0_ = 128 + lane < M0;
  bool a1 = lane < M1, b1_ = 64 + lane < M1, c1_ = 128 + lane < M1;

  // Michelot fixed point: tau = (sum_{z>tau} z - 1)/|{z>tau}| on compacted z
  float s0 = (a0 ? z0a : 0.f) + (b0_ ? z0b : 0.f) + (c0_ ? z0c : 0.f);
  float n0 = (a0 ? 1.f : 0.f) + (b0_ ? 1.f : 0.f) + (c0_ ? 1.f : 0.f);
  float s1 = (a1 ? z1a : 0.f) + (b1_ ? z1b : 0.f) + (c1_ ? z1c : 0.f);
  float n1 = (a1 ? 1.f : 0.f) + (b1_ ? 1.f : 0.f) + (c1_ ? 1.f : 0.f);
  red4(s0, n0, s1, n1);
  float tau0 = (s0 - 1.f) / n0, tau1 = (s1 - 1.f) / n1;
  float p0 = n0, p1 = n1;
  #pragma unroll 1
  for (int it = 0; it < 32; ++it){
    bool i0a = a0 && z0a > tau0, i0b = b0_ && z0b > tau0, i0c = c0_ && z0c > tau0;
    bool i1a = a1 && z1a > tau1, i1b = b1_ && z1b > tau1, i1c = c1_ && z1c > tau1;
    s0 = (i0a ? z0a : 0.f) + (i0b ? z0b : 0.f) + (i0c ? z0c : 0.f);
    n0 = (i0a ? 1.f : 0.f) + (i0b ? 1.f : 0.f) + (i0c ? 1.f : 0.f);
    s1 = (i1a ? z1a : 0.f) + (i1b ? z1b : 0.f) + (i1c ? z1c : 0.f);
    n1 = (i1a ? 1.f : 0.f) + (i1b ? 1.f : 0.f) + (i1c ? 1.f : 0.f);
    red4(s0, n0, s1, n1);
    bool stable = (n0 == p0) && (n1 == p1);
    tau0 = (s0 - 1.f) / n0; tau1 = (s1 - 1.f) / n1;
    p0 = n0; p1 = n1;
    if (stable) break;
  }

  // dense output, vectorized: lane owns cols [qtr*256 + lane*4, +4)
  float* o0 = out + ((size_t)(rowbase + row0) * NHEAD + h) * NSEQ;
  float* o1 = out + ((size_t)(rowbase + row1) * NHEAD + h) * NSEQ;
  int b0v = (lane & 15) << 2;
  unsigned long long pmask = (1ull << b0v) - 1ull;     // b0v==0 -> 0
  #pragma unroll
  for (int qtr = 0; qtr < 4; ++qtr){
    int cw = (qtr << 2) + (lane >> 4);
    unsigned long long w0 = mw[row0][cw], w1 = mw[row1][cw];
    int rk0 = (int)mp[row0][cw] + __popcll(w0 & pmask);
    int rk1 = (int)mp[row1][cw] + __popcll(w1 & pmask);
    float v0[4], v1[4];
    #pragma unroll
    for (int j = 0; j < 4; ++j){
      int bit0 = (int)((w0 >> (b0v + j)) & 1ull);
      int bit1 = (int)((w1 >> (b0v + j)) & 1ull);
      v0[j] = bit0 ? fmaxf(zlds[row0][rk0] * scale - tau0, 0.f) : 0.f;
      v1[j] = bit1 ? fmaxf(zlds[row1][rk1] * scale - tau1, 0.f) : 0.f;
      rk0 += bit0; rk1 += bit1;
    }
    ((float4*)o0)[(qtr << 6) + lane] = make_float4(v0[0], v0[1], v0[2], v0[3]);
    ((float4*)o1)[(qtr << 6) + lane] = make_float4(v1[0], v1[1], v1[2], v1[3]);
  }
}

extern "C" void kernel_launch(void* const* d_in, const int* in_sizes, int n_in,
                              void* d_out, int out_size, void* d_ws, size_t ws_size,
                              hipStream_t stream) {
  const float* Q  = (const float*)d_in[0];
  const float* V  = (const float*)d_in[1];
  const float* A  = (const float*)d_in[2];
  const float* WQ = (const float*)d_in[3];
  const float* bQ = (const float*)d_in[4];
  const float* WK = (const float*)d_in[5];
  const float* bK = (const float*)d_in[6];
  float* out = (float*)d_out;

  char* ws = (char*)d_ws;
  unsigned short*     qhi = (unsigned short*)ws;                          // 6.29 MB
  unsigned short*     qlo = (unsigned short*)(ws + (size_t)6291456);      // 6.29 MB
  unsigned short*     kf  = (unsigned short*)(ws + (size_t)12582912);     // 6.29 MB
  unsigned short*     wqt = (unsigned short*)(ws + (size_t)18874368);     // 0.20 MB
  unsigned short*     wkt = (unsigned short*)(ws + (size_t)19070976);     // 0.20 MB
  unsigned long long* bm  = (unsigned long long*)(ws + (size_t)19267584); // 1.05 MB
  unsigned short*     bmp = (unsigned short*)(ws + (size_t)20316160);     // 0.26 MB
  (void)in_sizes; (void)n_in; (void)out_size; (void)ws_size;

  prep_kernel<<<2816, 256, 0, stream>>>(WQ, WK, wqt, wkt, A, bm, bmp);
  proj2_kernel<<<dim3(128, 4, 2), 256, 0, stream>>>(Q, V, wqt, wkt, bQ, bK, qhi, qlo, kf);
  attn_kernel<<<3072, 512, 0, stream>>>(qhi, qlo, kf, bm, bmp, out);
}

// Round 12
// 85.994 us; speedup vs baseline: 2.5449x; 1.1310x over previous
//
#include <hip/hip_runtime.h>
#include <hip/hip_bf16.h>
#include <stdint.h>

#define DIMK 256
#define DIMV 384
#define NSEQ 1024
#define NHEAD 6
#define ZCAP 192

typedef __attribute__((ext_vector_type(8))) short short8;
typedef __attribute__((ext_vector_type(4))) float floatx4;

__device__ __forceinline__ unsigned short f2b(float f){
  unsigned int x = __float_as_uint(f);
  return (unsigned short)((x + 0x7fffu + ((x >> 16) & 1u)) >> 16);
}
__device__ __forceinline__ unsigned int pack2(float a, float b){
  return (unsigned int)f2b(a) | ((unsigned int)f2b(b) << 16);
}
__device__ __forceinline__ float blo(unsigned int u){ return __uint_as_float(u << 16); }

// Fused independent producers (flat grid, 256 thr):
//   bid < 768 : W transpose+convert -> wqt/wkt bf16 [384][256]
//   bid >= 768: A -> row bitmask (16 u64/row) + exclusive word-prefix popcounts
__global__ __launch_bounds__(256) void prep_kernel(
    const float* __restrict__ WQ, const float* __restrict__ WK,
    unsigned short* __restrict__ wqt, unsigned short* __restrict__ wkt,
    const float* __restrict__ A,
    unsigned long long* __restrict__ bm, unsigned short* __restrict__ bmp)
{
  int bid = blockIdx.x;
  if (bid < 768){
    int i = bid * 256 + threadIdx.x;
    const float* W; unsigned short* O; int idx;
    if (i < 98304){ W = WQ; O = wqt; idx = i; }
    else          { W = WK; O = wkt; idx = i - 98304; }
    int n = idx >> 8;
    int k = idx & 255;
    O[idx] = f2b(W[(size_t)k * 384 + n]);
  } else {
    int r = (bid - 768) * 4 + (threadIdx.x >> 6);
    int lane = threadIdx.x & 63;
    const float* arow = A + (size_t)r * NSEQ;
    unsigned long long myw = 0;
    #pragma unroll
    for (int c = 0; c < 16; ++c){
      unsigned long long m = __ballot(arow[c * 64 + lane] > 0.5f);
      if (lane == c) myw = m;
    }
    int own = (lane < 16) ? __popcll(myw) : 0;
    int inc = own;
    #pragma unroll
    for (int o = 1; o < 16; o <<= 1){
      int t = __shfl_up(inc, o, 16);
      if ((lane & 15) >= o) inc += t;
    }
    if (lane < 16){
      bm [(size_t)r * 16 + lane] = myw;
      bmp[(size_t)r * 16 + lane] = (unsigned short)(inc - own);
    }
  }
}

// Merged projections -> MFMA-fragment-major layouts.
// frag coords for value at (seq-pos n, feature d, slice=b*6+h):
//   dst = (((slice*2 + (d>>5))*64 + (n>>4))*64 + ((d>>3)&3)*16 + (n&15))*8 + (d&7)
// z=0: q -> qhi + qlo (bf16 hi/lo split), PRE-SCALED by 1/sqrt(384)
// z=1: k -> kf (bf16)
__global__ __launch_bounds__(256) void proj2_kernel(
    const float* __restrict__ Q, const float* __restrict__ V,
    const unsigned short* __restrict__ wqt, const unsigned short* __restrict__ wkt,
    const float* __restrict__ bQ, const float* __restrict__ bK,
    unsigned short* __restrict__ qhi, unsigned short* __restrict__ qlo,
    unsigned short* __restrict__ kf)
{
  __shared__ uint4 lA[512];
  __shared__ uint4 lB[864];
  int which = blockIdx.z;
  const float* X = which ? V : Q;
  const unsigned short* Wt = which ? wkt : wqt;
  const float* bias = which ? bK : bQ;

  int t = threadIdx.x;
  int lane = t & 63, wave = t >> 6;
  int wm = wave >> 1, wn = wave & 1;
  int rb = blockIdx.x * 64;
  int nb = blockIdx.y * 96;
  floatx4 acc[2][3];
  #pragma unroll
  for (int mi = 0; mi < 2; ++mi)
    #pragma unroll
    for (int ni = 0; ni < 3; ++ni) acc[mi][ni] = (floatx4){0.f, 0.f, 0.f, 0.f};

  for (int it = 0; it < 4; ++it){
    int k0 = it * 64;
    #pragma unroll
    for (int i = 0; i < 2; ++i){
      int c = t + i * 256;
      int kc = c >> 6, row = c & 63;
      const float* src = X + (size_t)(rb + row) * DIMK + k0 + kc * 8;
      float4 f0 = *(const float4*)src;
      float4 f1 = *(const float4*)(src + 4);
      uint4 w;
      w.x = pack2(f0.x, f0.y); w.y = pack2(f0.z, f0.w);
      w.z = pack2(f1.x, f1.y); w.w = pack2(f1.z, f1.w);
      lA[c] = w;
    }
    #pragma unroll
    for (int i = 0; i < 3; ++i){
      int c = t + i * 256;
      int n = c >> 3, kc = c & 7;
      uint4 v = *(const uint4*)(Wt + (size_t)(nb + n) * DIMK + k0 + kc * 8);
      lB[n * 9 + kc] = v;
    }
    __syncthreads();
    #pragma unroll
    for (int kk = 0; kk < 2; ++kk){
      int kc  = kk * 4 + (lane >> 4);
      int r16 = lane & 15;
      short8 af[2], bf[3];
      #pragma unroll
      for (int mi = 0; mi < 2; ++mi)
        af[mi] = *(const short8*)&lA[kc * 64 + wm * 32 + mi * 16 + r16];
      #pragma unroll
      for (int ni = 0; ni < 3; ++ni)
        bf[ni] = *(const short8*)&lB[(wn * 48 + ni * 16 + r16) * 9 + kc];
      #pragma unroll
      for (int mi = 0; mi < 2; ++mi)
        #pragma unroll
        for (int ni = 0; ni < 3; ++ni)
          acc[mi][ni] = __builtin_amdgcn_mfma_f32_16x16x32_bf16(af[mi], bf[ni], acc[mi][ni], 0, 0, 0);
    }
    __syncthreads();
  }
  const float scale = 0.05103103630798288f;    // 1/sqrt(384), folded into q
  int r16 = lane & 15, rq = lane >> 4;
  #pragma unroll
  for (int ni = 0; ni < 3; ++ni){
    int col = nb + wn * 48 + ni * 16 + r16;
    float bv = bias[col];
    int h = col >> 6, d = col & 63;
    #pragma unroll
    for (int mi = 0; mi < 2; ++mi){
      #pragma unroll
      for (int q = 0; q < 4; ++q){
        int row = rb + wm * 32 + mi * 16 + rq * 4 + q;
        int bb = row >> 10, n = row & 1023;
        int slice = bb * NHEAD + h;
        size_t dst = ((((size_t)slice * 2 + (d >> 5)) * 64 + (n >> 4)) * 64
                      + ((d >> 3) & 3) * 16 + (n & 15)) * 8 + (d & 7);
        float v = acc[mi][ni][q] + bv;
        if (which){
          kf[dst] = f2b(v);
        } else {
          v *= scale;
          unsigned short hi_ = f2b(v);
          qhi[dst] = hi_;
          qlo[dst] = f2b(v - blo((unsigned int)hi_));
        }
      }
    }
  }
}

__device__ __forceinline__ void red2(float& a, float& b){
  #pragma unroll
  for (int o = 1; o < 64; o <<= 1){ a += __shfl_xor(a, o); b += __shfl_xor(b, o); }
}
__device__ __forceinline__ void red4(float& a, float& b, float& c, float& d){
  #pragma unroll
  for (int o = 1; o < 64; o <<= 1){
    a += __shfl_xor(a, o); b += __shfl_xor(b, o);
    c += __shfl_xor(c, o); d += __shfl_xor(d, o);
  }
}

// Dense MFMA attn with COMPACTED logits (r10/r11 structure).
// q pre-scaled -> zlds holds final logits. Wave-uniform fast path for
// M<=64 (94%): 1-chunk Michelot, ballot/popc support counts, red2 only.
__global__ __launch_bounds__(512) void attn_kernel(
    const unsigned short* __restrict__ qhi, const unsigned short* __restrict__ qlo,
    const unsigned short* __restrict__ kf, const unsigned long long* __restrict__ bm,
    const unsigned short* __restrict__ bmp, float* __restrict__ out)
{
  __shared__ unsigned long long mw[16][16];
  __shared__ unsigned short    mp[16][16];
  __shared__ float             zlds[16][ZCAP + 1];

  int bid = blockIdx.x;
  int x = bid & 7;            // batch == XCD
  int u = bid >> 3;           // 0..383
  int h = u >> 6;             // head
  int rb = u & 63;            // 16-row block
  int tid = threadIdx.x;
  int lane = tid & 63, w = tid >> 6;
  int slice = x * NHEAD + h;
  int rowbase = (x << 10) + (rb << 4);

  if (tid < 256){
    int rr = tid >> 4, ww = tid & 15;
    mw[rr][ww] = bm [((size_t)(rowbase + rr)) * 16 + ww];
    mp[rr][ww] = bmp[((size_t)(rowbase + rr)) * 16 + ww];
  }

  const short8* qh8 = (const short8*)qhi;
  const short8* ql8 = (const short8*)qlo;
  const short8* kf8 = (const short8*)kf;
  size_t ab0 = (((size_t)slice * 2 + 0) * 64 + rb) * 64 + lane;
  size_t ab1 = (((size_t)slice * 2 + 1) * 64 + rb) * 64 + lane;
  short8 ah0 = qh8[ab0], al0 = ql8[ab0];
  short8 ah1 = qh8[ab1], al1 = ql8[ab1];
  __syncthreads();

  #pragma unroll
  for (int i = 0; i < 8; ++i){
    int tt = (w << 3) + i;
    short8 b0 = kf8[(((size_t)slice * 2 + 0) * 64 + tt) * 64 + lane];
    short8 b1 = kf8[(((size_t)slice * 2 + 1) * 64 + tt) * 64 + lane];
    floatx4 a = (floatx4){0.f, 0.f, 0.f, 0.f};
    a = __builtin_amdgcn_mfma_f32_16x16x32_bf16(al0, b0, a, 0, 0, 0);
    a = __builtin_amdgcn_mfma_f32_16x16x32_bf16(ah0, b0, a, 0, 0, 0);
    a = __builtin_amdgcn_mfma_f32_16x16x32_bf16(al1, b1, a, 0, 0, 0);
    a = __builtin_amdgcn_mfma_f32_16x16x32_bf16(ah1, b1, a, 0, 0, 0);
    int colb = (w << 7) + (i << 4) + (lane & 15);
    int cw = colb >> 6, cb = colb & 63;
    unsigned long long below = (1ull << cb) - 1ull;
    #pragma unroll
    for (int reg = 0; reg < 4; ++reg){
      int rowz = ((lane >> 4) << 2) + reg;       // C/D: col=lane&15, row=(lane>>4)*4+reg
      unsigned long long word = mw[rowz][cw];
      if ((word >> cb) & 1){
        int rank = (int)mp[rowz][cw] + __popcll(word & below);
        if (rank < ZCAP) zlds[rowz][rank] = a[reg];
      }
    }
  }
  __syncthreads();

  int row0 = w * 2, row1 = w * 2 + 1;
  int M0 = (int)mp[row0][15] + __popcll(mw[row0][15]);
  int M1 = (int)mp[row1][15] + __popcll(mw[row1][15]);
  float tau0, tau1;

  if (M0 <= 64 && M1 <= 64){
    // ---- fast path (94%): 1 chunk, ballot counts, red2 ----
    bool a0 = lane < M0, a1 = lane < M1;
    float z0 = a0 ? zlds[row0][lane] : 0.f;
    float z1 = a1 ? zlds[row1][lane] : 0.f;
    float s0 = z0, s1 = z1;
    red2(s0, s1);
    tau0 = (s0 - 1.f) / (float)M0;
    tau1 = (s1 - 1.f) / (float)M1;
    int p0 = M0, p1 = M1;
    #pragma unroll 1
    for (int it = 0; it < 32; ++it){
      bool i0 = a0 && z0 > tau0, i1 = a1 && z1 > tau1;
      int n0 = __popcll(__ballot(i0));
      int n1 = __popcll(__ballot(i1));
      s0 = i0 ? z0 : 0.f; s1 = i1 ? z1 : 0.f;
      red2(s0, s1);
      bool stable = (n0 == p0) && (n1 == p1);
      tau0 = (s0 - 1.f) / (float)n0;
      tau1 = (s1 - 1.f) / (float)n1;
      p0 = n0; p1 = n1;
      if (stable) break;
    }
  } else {
    // ---- generic path: 3 register chunks (cap 192) ----
    float z0a = (lane < M0)       ? zlds[row0][lane]       : 0.f;
    float z1a = (lane < M1)       ? zlds[row1][lane]       : 0.f;
    float z0b = (64 + lane < M0)  ? zlds[row0][64 + lane]  : 0.f;
    float z1b = (64 + lane < M1)  ? zlds[row1][64 + lane]  : 0.f;
    float z0c = (128 + lane < M0) ? zlds[row0][128 + lane] : 0.f;
    float z1c = (128 + lane < M1) ? zlds[row1][128 + lane] : 0.f;
    bool a0 = lane < M0, b0_ = 64 + lane < M0, c0_ = 128 + lane < M0;
    bool a1 = lane < M1, b1_ = 64 + lane < M1, c1_ = 128 + lane < M1;
    float s0 = (a0 ? z0a : 0.f) + (b0_ ? z0b : 0.f) + (c0_ ? z0c : 0.f);
    float n0 = (a0 ? 1.f : 0.f) + (b0_ ? 1.f : 0.f) + (c0_ ? 1.f : 0.f);
    float s1 = (a1 ? z1a : 0.f) + (b1_ ? z1b : 0.f) + (c1_ ? z1c : 0.f);
    float n1 = (a1 ? 1.f : 0.f) + (b1_ ? 1.f : 0.f) + (c1_ ? 1.f : 0.f);
    red4(s0, n0, s1, n1);
    tau0 = (s0 - 1.f) / n0; tau1 = (s1 - 1.f) / n1;
    float p0 = n0, p1 = n1;
    #pragma unroll 1
    for (int it = 0; it < 32; ++it){
      bool i0a = a0 && z0a > tau0, i0b = b0_ && z0b > tau0, i0c = c0_ && z0c > tau0;
      bool i1a = a1 && z1a > tau1, i1b = b1_ && z1b > tau1, i1c = c1_ && z1c > tau1;
      s0 = (i0a ? z0a : 0.f) + (i0b ? z0b : 0.f) + (i0c ? z0c : 0.f);
      n0 = (i0a ? 1.f : 0.f) + (i0b ? 1.f : 0.f) + (i0c ? 1.f : 0.f);
      s1 = (i1a ? z1a : 0.f) + (i1b ? z1b : 0.f) + (i1c ? z1c : 0.f);
      n1 = (i1a ? 1.f : 0.f) + (i1b ? 1.f : 0.f) + (i1c ? 1.f : 0.f);
      red4(s0, n0, s1, n1);
      bool stable = (n0 == p0) && (n1 == p1);
      tau0 = (s0 - 1.f) / n0; tau1 = (s1 - 1.f) / n1;
      p0 = n0; p1 = n1;
      if (stable) break;
    }
  }

  // dense output, vectorized: lane owns cols [qtr*256 + lane*4, +4)
  float* o0 = out + ((size_t)(rowbase + row0) * NHEAD + h) * NSEQ;
  float* o1 = out + ((size_t)(rowbase + row1) * NHEAD + h) * NSEQ;
  int b0v = (lane & 15) << 2;
  unsigned long long pmask = (1ull << b0v) - 1ull;     // b0v==0 -> 0
  #pragma unroll
  for (int qtr = 0; qtr < 4; ++qtr){
    int cw = (qtr << 2) + (lane >> 4);
    unsigned long long w0 = mw[row0][cw], w1 = mw[row1][cw];
    int rk0 = (int)mp[row0][cw] + __popcll(w0 & pmask);
    int rk1 = (int)mp[row1][cw] + __popcll(w1 & pmask);
    float v0[4], v1[4];
    #pragma unroll
    for (int j = 0; j < 4; ++j){
      int bit0 = (int)((w0 >> (b0v + j)) & 1ull);
      int bit1 = (int)((w1 >> (b0v + j)) & 1ull);
      v0[j] = bit0 ? fmaxf(zlds[row0][rk0] - tau0, 0.f) : 0.f;
      v1[j] = bit1 ? fmaxf(zlds[row1][rk1] - tau1, 0.f) : 0.f;
      rk0 += bit0; rk1 += bit1;
    }
    ((float4*)o0)[(qtr << 6) + lane] = make_float4(v0[0], v0[1], v0[2], v0[3]);
    ((float4*)o1)[(qtr << 6) + lane] = make_float4(v1[0], v1[1], v1[2], v1[3]);
  }
}

extern "C" void kernel_launch(void* const* d_in, const int* in_sizes, int n_in,
                              void* d_out, int out_size, void* d_ws, size_t ws_size,
                              hipStream_t stream) {
  const float* Q  = (const float*)d_in[0];
  const float* V  = (const float*)d_in[1];
  const float* A  = (const float*)d_in[2];
  const float* WQ = (const float*)d_in[3];
  const float* bQ = (const float*)d_in[4];
  const float* WK = (const float*)d_in[5];
  const float* bK = (const float*)d_in[6];
  float* out = (float*)d_out;

  char* ws = (char*)d_ws;
  unsigned short*     qhi = (unsigned short*)ws;                          // 6.29 MB
  unsigned short*     qlo = (unsigned short*)(ws + (size_t)6291456);      // 6.29 MB
  unsigned short*     kf  = (unsigned short*)(ws + (size_t)12582912);     // 6.29 MB
  unsigned short*     wqt = (unsigned short*)(ws + (size_t)18874368);     // 0.20 MB
  unsigned short*     wkt = (unsigned short*)(ws + (size_t)19070976);     // 0.20 MB
  unsigned long long* bm  = (unsigned long long*)(ws + (size_t)19267584); // 1.05 MB
  unsigned short*     bmp = (unsigned short*)(ws + (size_t)20316160);     // 0.26 MB
  (void)in_sizes; (void)n_in; (void)out_size; (void)ws_size;

  prep_kernel<<<2816, 256, 0, stream>>>(WQ, WK, wqt, wkt, A, bm, bmp);
  proj2_kernel<<<dim3(128, 4, 2), 256, 0, stream>>>(Q, V, wqt, wkt, bQ, bK, qhi, qlo, kf);
  attn_kernel<<<3072, 512, 0, stream>>>(qhi, qlo, kf, bm, bmp, out);
}

// Round 13
// 85.562 us; speedup vs baseline: 2.5578x; 1.0050x over previous
//
#include <hip/hip_runtime.h>
#include <hip/hip_bf16.h>
#include <stdint.h>

#define DIMK 256
#define DIMV 384
#define NSEQ 1024
#define NHEAD 6
#define ZCAP 192

typedef __attribute__((ext_vector_type(8))) short short8;
typedef __attribute__((ext_vector_type(4))) float floatx4;

__device__ __forceinline__ unsigned short f2b(float f){
  unsigned int x = __float_as_uint(f);
  return (unsigned short)((x + 0x7fffu + ((x >> 16) & 1u)) >> 16);
}
__device__ __forceinline__ unsigned int pack2(float a, float b){
  return (unsigned int)f2b(a) | ((unsigned int)f2b(b) << 16);
}
__device__ __forceinline__ float blo(unsigned int u){ return __uint_as_float(u << 16); }

// ---------------- fused pre-pass: proj (blocks 0..1023) + maskbits (1024..3071)
// proj: Y = bf16(X[8192][256]) @ bf16(W)[256][384] + bias -> fragment-major.
//   B-panel staged DIRECTLY from W f32 (in-register f32->bf16 transpose into
//   the same [n][72-u16] LDS layout as the old pre-transposed path).
// frag coords for (seq n, feature d, slice=b*6+h):
//   dst = (((slice*2 + (d>>5))*64 + (n>>4))*64 + ((d>>3)&3)*16 + (n&15))*8 + (d&7)
// z=0: q -> qhi+qlo (hi/lo split, PRE-SCALED by 1/sqrt(384));  z=1: k -> kf
__global__ __launch_bounds__(256) void fused_pre_kernel(
    const float* __restrict__ Q, const float* __restrict__ V,
    const float* __restrict__ WQ, const float* __restrict__ WK,
    const float* __restrict__ bQ, const float* __restrict__ bK,
    const float* __restrict__ A,
    unsigned short* __restrict__ qhi, unsigned short* __restrict__ qlo,
    unsigned short* __restrict__ kf,
    unsigned long long* __restrict__ bm, unsigned short* __restrict__ bmp)
{
  int bid = blockIdx.x;
  if (bid >= 1024){
    // ---- maskbits: A -> row bitmask + exclusive word-prefix popcounts ----
    int r = (bid - 1024) * 4 + (threadIdx.x >> 6);
    int lane = threadIdx.x & 63;
    const float* arow = A + (size_t)r * NSEQ;
    unsigned long long myw = 0;
    #pragma unroll
    for (int c = 0; c < 16; ++c){
      unsigned long long m = __ballot(arow[c * 64 + lane] > 0.5f);
      if (lane == c) myw = m;
    }
    int own = (lane < 16) ? __popcll(myw) : 0;
    int inc = own;
    #pragma unroll
    for (int o = 1; o < 16; o <<= 1){
      int t = __shfl_up(inc, o, 16);
      if ((lane & 15) >= o) inc += t;
    }
    if (lane < 16){
      bm [(size_t)r * 16 + lane] = myw;
      bmp[(size_t)r * 16 + lane] = (unsigned short)(inc - own);
    }
    return;
  }

  // ---- proj path ----
  __shared__ uint4 lA[512];                    // [kc 0..7][row 0..63]
  __shared__ unsigned short lB16[96 * 72];     // [n 0..95][k 0..63, pitch 72]
  int which = bid >> 9;                        // 0: q, 1: k
  int rem = bid & 511;
  int bx = rem >> 2, by = rem & 3;
  const float* X = which ? V : Q;
  const float* W = which ? WK : WQ;
  const float* bias = which ? bK : bQ;

  int t = threadIdx.x;
  int lane = t & 63, wave = t >> 6;
  int wm = wave >> 1, wn = wave & 1;
  int rb = bx * 64;
  int nb = by * 96;
  floatx4 acc[2][3];
  #pragma unroll
  for (int mi = 0; mi < 2; ++mi)
    #pragma unroll
    for (int ni = 0; ni < 3; ++ni) acc[mi][ni] = (floatx4){0.f, 0.f, 0.f, 0.f};

  for (int it = 0; it < 4; ++it){
    int k0 = it * 64;
    // stage A: f32 -> bf16 in registers (coalesced)
    #pragma unroll
    for (int i = 0; i < 2; ++i){
      int c = t + i * 256;
      int kc = c >> 6, row = c & 63;
      const float* src = X + (size_t)(rb + row) * DIMK + k0 + kc * 8;
      float4 f0 = *(const float4*)src;
      float4 f1 = *(const float4*)(src + 4);
      uint4 w;
      w.x = pack2(f0.x, f0.y); w.y = pack2(f0.z, f0.w);
      w.z = pack2(f1.x, f1.y); w.w = pack2(f1.z, f1.w);
      lA[c] = w;
    }
    // stage B from raw W (in-register transpose): 1536 float4s, 6/thread
    #pragma unroll
    for (int i = 0; i < 6; ++i){
      int c = t + i * 256;
      int kk2 = c / 24, f4 = c % 24;           // k-row, float4 within 96 cols
      float4 wv = *(const float4*)(W + (size_t)(k0 + kk2) * DIMV + nb + f4 * 4);
      int n0 = f4 * 4;
      lB16[(n0    ) * 72 + kk2] = f2b(wv.x);
      lB16[(n0 + 1) * 72 + kk2] = f2b(wv.y);
      lB16[(n0 + 2) * 72 + kk2] = f2b(wv.z);
      lB16[(n0 + 3) * 72 + kk2] = f2b(wv.w);
    }
    __syncthreads();
    #pragma unroll
    for (int kk = 0; kk < 2; ++kk){
      int kc  = kk * 4 + (lane >> 4);
      int r16 = lane & 15;
      short8 af[2], bf[3];
      #pragma unroll
      for (int mi = 0; mi < 2; ++mi)
        af[mi] = *(const short8*)&lA[kc * 64 + wm * 32 + mi * 16 + r16];
      #pragma unroll
      for (int ni = 0; ni < 3; ++ni)
        bf[ni] = *(const short8*)&lB16[(wn * 48 + ni * 16 + r16) * 72 + kc * 8];
      #pragma unroll
      for (int mi = 0; mi < 2; ++mi)
        #pragma unroll
        for (int ni = 0; ni < 3; ++ni)
          acc[mi][ni] = __builtin_amdgcn_mfma_f32_16x16x32_bf16(af[mi], bf[ni], acc[mi][ni], 0, 0, 0);
    }
    __syncthreads();
  }
  const float scale = 0.05103103630798288f;    // 1/sqrt(384), folded into q
  int r16 = lane & 15, rq = lane >> 4;
  #pragma unroll
  for (int ni = 0; ni < 3; ++ni){
    int col = nb + wn * 48 + ni * 16 + r16;
    float bv = bias[col];
    int h = col >> 6, d = col & 63;
    #pragma unroll
    for (int mi = 0; mi < 2; ++mi){
      #pragma unroll
      for (int q = 0; q < 4; ++q){
        int row = rb + wm * 32 + mi * 16 + rq * 4 + q;
        int bb = row >> 10, n = row & 1023;
        int slice = bb * NHEAD + h;
        size_t dst = ((((size_t)slice * 2 + (d >> 5)) * 64 + (n >> 4)) * 64
                      + ((d >> 3) & 3) * 16 + (n & 15)) * 8 + (d & 7);
        float v = acc[mi][ni][q] + bv;
        if (which){
          kf[dst] = f2b(v);
        } else {
          v *= scale;
          unsigned short hi_ = f2b(v);
          qhi[dst] = hi_;
          qlo[dst] = f2b(v - blo((unsigned int)hi_));
        }
      }
    }
  }
}

__device__ __forceinline__ void red2(float& a, float& b){
  #pragma unroll
  for (int o = 1; o < 64; o <<= 1){ a += __shfl_xor(a, o); b += __shfl_xor(b, o); }
}
__device__ __forceinline__ void red4(float& a, float& b, float& c, float& d){
  #pragma unroll
  for (int o = 1; o < 64; o <<= 1){
    a += __shfl_xor(a, o); b += __shfl_xor(b, o);
    c += __shfl_xor(c, o); d += __shfl_xor(d, o);
  }
}

// Dense MFMA attn with COMPACTED logits (r12 structure, unchanged) + setprio
// around the MFMA loop (T5: blocks at different phases -> scheduler can favor
// the MFMA-issuing waves).
__global__ __launch_bounds__(512) void attn_kernel(
    const unsigned short* __restrict__ qhi, const unsigned short* __restrict__ qlo,
    const unsigned short* __restrict__ kf, const unsigned long long* __restrict__ bm,
    const unsigned short* __restrict__ bmp, float* __restrict__ out)
{
  __shared__ unsigned long long mw[16][16];
  __shared__ unsigned short    mp[16][16];
  __shared__ float             zlds[16][ZCAP + 1];

  int bid = blockIdx.x;
  int x = bid & 7;            // batch == XCD
  int u = bid >> 3;           // 0..383
  int h = u >> 6;             // head
  int rb = u & 63;            // 16-row block
  int tid = threadIdx.x;
  int lane = tid & 63, w = tid >> 6;
  int slice = x * NHEAD + h;
  int rowbase = (x << 10) + (rb << 4);

  if (tid < 256){
    int rr = tid >> 4, ww = tid & 15;
    mw[rr][ww] = bm [((size_t)(rowbase + rr)) * 16 + ww];
    mp[rr][ww] = bmp[((size_t)(rowbase + rr)) * 16 + ww];
  }

  const short8* qh8 = (const short8*)qhi;
  const short8* ql8 = (const short8*)qlo;
  const short8* kf8 = (const short8*)kf;
  size_t ab0 = (((size_t)slice * 2 + 0) * 64 + rb) * 64 + lane;
  size_t ab1 = (((size_t)slice * 2 + 1) * 64 + rb) * 64 + lane;
  short8 ah0 = qh8[ab0], al0 = ql8[ab0];
  short8 ah1 = qh8[ab1], al1 = ql8[ab1];
  __syncthreads();

  __builtin_amdgcn_s_setprio(1);
  #pragma unroll
  for (int i = 0; i < 8; ++i){
    int tt = (w << 3) + i;
    short8 b0 = kf8[(((size_t)slice * 2 + 0) * 64 + tt) * 64 + lane];
    short8 b1 = kf8[(((size_t)slice * 2 + 1) * 64 + tt) * 64 + lane];
    floatx4 a = (floatx4){0.f, 0.f, 0.f, 0.f};
    a = __builtin_amdgcn_mfma_f32_16x16x32_bf16(al0, b0, a, 0, 0, 0);
    a = __builtin_amdgcn_mfma_f32_16x16x32_bf16(ah0, b0, a, 0, 0, 0);
    a = __builtin_amdgcn_mfma_f32_16x16x32_bf16(al1, b1, a, 0, 0, 0);
    a = __builtin_amdgcn_mfma_f32_16x16x32_bf16(ah1, b1, a, 0, 0, 0);
    int colb = (w << 7) + (i << 4) + (lane & 15);
    int cw = colb >> 6, cb = colb & 63;
    unsigned long long below = (1ull << cb) - 1ull;
    #pragma unroll
    for (int reg = 0; reg < 4; ++reg){
      int rowz = ((lane >> 4) << 2) + reg;       // C/D: col=lane&15, row=(lane>>4)*4+reg
      unsigned long long word = mw[rowz][cw];
      if ((word >> cb) & 1){
        int rank = (int)mp[rowz][cw] + __popcll(word & below);
        if (rank < ZCAP) zlds[rowz][rank] = a[reg];
      }
    }
  }
  __builtin_amdgcn_s_setprio(0);
  __syncthreads();

  int row0 = w * 2, row1 = w * 2 + 1;
  int M0 = (int)mp[row0][15] + __popcll(mw[row0][15]);
  int M1 = (int)mp[row1][15] + __popcll(mw[row1][15]);
  float tau0, tau1;

  if (M0 <= 64 && M1 <= 64){
    // ---- fast path (94%): 1 chunk, ballot counts, red2 ----
    bool a0 = lane < M0, a1 = lane < M1;
    float z0 = a0 ? zlds[row0][lane] : 0.f;
    float z1 = a1 ? zlds[row1][lane] : 0.f;
    float s0 = z0, s1 = z1;
    red2(s0, s1);
    tau0 = (s0 - 1.f) / (float)M0;
    tau1 = (s1 - 1.f) / (float)M1;
    int p0 = M0, p1 = M1;
    #pragma unroll 1
    for (int it = 0; it < 32; ++it){
      bool i0 = a0 && z0 > tau0, i1 = a1 && z1 > tau1;
      int n0 = __popcll(__ballot(i0));
      int n1 = __popcll(__ballot(i1));
      s0 = i0 ? z0 : 0.f; s1 = i1 ? z1 : 0.f;
      red2(s0, s1);
      bool stable = (n0 == p0) && (n1 == p1);
      tau0 = (s0 - 1.f) / (float)n0;
      tau1 = (s1 - 1.f) / (float)n1;
      p0 = n0; p1 = n1;
      if (stable) break;
    }
  } else {
    // ---- generic path: 3 register chunks (cap 192) ----
    float z0a = (lane < M0)       ? zlds[row0][lane]       : 0.f;
    float z1a = (lane < M1)       ? zlds[row1][lane]       : 0.f;
    float z0b = (64 + lane < M0)  ? zlds[row0][64 + lane]  : 0.f;
    float z1b = (64 + lane < M1)  ? zlds[row1][64 + lane]  : 0.f;
    float z0c = (128 + lane < M0) ? zlds[row0][128 + lane] : 0.f;
    float z1c = (128 + lane < M1) ? zlds[row1][128 + lane] : 0.f;
    bool a0 = lane < M0, b0_ = 64 + lane < M0, c0_ = 128 + lane < M0;
    bool a1 = lane < M1, b1_ = 64 + lane < M1, c1_ = 128 + lane < M1;
    float s0 = (a0 ? z0a : 0.f) + (b0_ ? z0b : 0.f) + (c0_ ? z0c : 0.f);
    float n0 = (a0 ? 1.f : 0.f) + (b0_ ? 1.f : 0.f) + (c0_ ? 1.f : 0.f);
    float s1 = (a1 ? z1a : 0.f) + (b1_ ? z1b : 0.f) + (c1_ ? z1c : 0.f);
    float n1 = (a1 ? 1.f : 0.f) + (b1_ ? 1.f : 0.f) + (c1_ ? 1.f : 0.f);
    red4(s0, n0, s1, n1);
    tau0 = (s0 - 1.f) / n0; tau1 = (s1 - 1.f) / n1;
    float p0 = n0, p1 = n1;
    #pragma unroll 1
    for (int it = 0; it < 32; ++it){
      bool i0a = a0 && z0a > tau0, i0b = b0_ && z0b > tau0, i0c = c0_ && z0c > tau0;
      bool i1a = a1 && z1a > tau1, i1b = b1_ && z1b > tau1, i1c = c1_ && z1c > tau1;
      s0 = (i0a ? z0a : 0.f) + (i0b ? z0b : 0.f) + (i0c ? z0c : 0.f);
      n0 = (i0a ? 1.f : 0.f) + (i0b ? 1.f : 0.f) + (i0c ? 1.f : 0.f);
      s1 = (i1a ? z1a : 0.f) + (i1b ? z1b : 0.f) + (i1c ? z1c : 0.f);
      n1 = (i1a ? 1.f : 0.f) + (i1b ? 1.f : 0.f) + (i1c ? 1.f : 0.f);
      red4(s0, n0, s1, n1);
      bool stable = (n0 == p0) && (n1 == p1);
      tau0 = (s0 - 1.f) / n0; tau1 = (s1 - 1.f) / n1;
      p0 = n0; p1 = n1;
      if (stable) break;
    }
  }

  // dense output, vectorized: lane owns cols [qtr*256 + lane*4, +4)
  float* o0 = out + ((size_t)(rowbase + row0) * NHEAD + h) * NSEQ;
  float* o1 = out + ((size_t)(rowbase + row1) * NHEAD + h) * NSEQ;
  int b0v = (lane & 15) << 2;
  unsigned long long pmask = (1ull << b0v) - 1ull;     // b0v==0 -> 0
  #pragma unroll
  for (int qtr = 0; qtr < 4; ++qtr){
    int cw = (qtr << 2) + (lane >> 4);
    unsigned long long w0 = mw[row0][cw], w1 = mw[row1][cw];
    int rk0 = (int)mp[row0][cw] + __popcll(w0 & pmask);
    int rk1 = (int)mp[row1][cw] + __popcll(w1 & pmask);
    float v0[4], v1[4];
    #pragma unroll
    for (int j = 0; j < 4; ++j){
      int bit0 = (int)((w0 >> (b0v + j)) & 1ull);
      int bit1 = (int)((w1 >> (b0v + j)) & 1ull);
      v0[j] = bit0 ? fmaxf(zlds[row0][rk0] - tau0, 0.f) : 0.f;
      v1[j] = bit1 ? fmaxf(zlds[row1][rk1] - tau1, 0.f) : 0.f;
      rk0 += bit0; rk1 += bit1;
    }
    ((float4*)o0)[(qtr << 6) + lane] = make_float4(v0[0], v0[1], v0[2], v0[3]);
    ((float4*)o1)[(qtr << 6) + lane] = make_float4(v1[0], v1[1], v1[2], v1[3]);
  }
}

extern "C" void kernel_launch(void* const* d_in, const int* in_sizes, int n_in,
                              void* d_out, int out_size, void* d_ws, size_t ws_size,
                              hipStream_t stream) {
  const float* Q  = (const float*)d_in[0];
  const float* V  = (const float*)d_in[1];
  const float* A  = (const float*)d_in[2];
  const float* WQ = (const float*)d_in[3];
  const float* bQ = (const float*)d_in[4];
  const float* WK = (const float*)d_in[5];
  const float* bK = (const float*)d_in[6];
  float* out = (float*)d_out;

  char* ws = (char*)d_ws;
  unsigned short*     qhi = (unsigned short*)ws;                          // 6.29 MB
  unsigned short*     qlo = (unsigned short*)(ws + (size_t)6291456);      // 6.29 MB
  unsigned short*     kf  = (unsigned short*)(ws + (size_t)12582912);     // 6.29 MB
  unsigned long long* bm  = (unsigned long long*)(ws + (size_t)19267584); // 1.05 MB
  unsigned short*     bmp = (unsigned short*)(ws + (size_t)20316160);     // 0.26 MB
  (void)in_sizes; (void)n_in; (void)out_size; (void)ws_size;

  fused_pre_kernel<<<3072, 256, 0, stream>>>(Q, V, WQ, WK, bQ, bK, A,
                                             qhi, qlo, kf, bm, bmp);
  attn_kernel<<<3072, 512, 0, stream>>>(qhi, qlo, kf, bm, bmp, out);
}